// Round 4
// baseline (2418.548 us; speedup 1.0000x reference)
//
#include <hip/hip_runtime.h>
#include <math.h>

// ---------------- constants ----------------
#define S_ 2
#define B_ 8
#define N_ 12
#define A_ 4
#define L_ 24
#define C_ 256
#define AUX_ 16
#define EK_ 64
#define K_ 256
#define M_ 8
#define OTH_ 32
#define D2_ 272
#define FF_ 2048
#define RIN_ 736
#define NSTR_ (S_*B_*N_*A_)   // 768

// ---------------- K0: renorm char table (max_norm=1) ----------------
__global__ void scale_table_k(const float* __restrict__ tbl, float* __restrict__ out) {
    int r = blockIdx.x;          // 128 rows
    int c = threadIdx.x;         // 256
    float v = tbl[r * C_ + c];
    float sq = v * v;
    for (int off = 32; off; off >>= 1) sq += __shfl_down(sq, off);
    __shared__ float red[4];
    __shared__ float scl;
    if ((c & 63) == 0) red[c >> 6] = sq;
    __syncthreads();
    if (c == 0) {
        float n = sqrtf(red[0] + red[1] + red[2] + red[3]);
        scl = fminf(1.f, 1.f / fmaxf(n, 1e-7f));
    }
    __syncthreads();
    out[r * C_ + c] = v * scl;
}

// ---------------- K1: gated conv / keyword path -> x1 layout ----------------
// tanh(pf)*sig(pg) = (e^{2pf}-1) e^{pg} / ((e^{2pf}+1)(e^{pg}+1)) : 2 exp + 1 rcp
__global__ void attvec_k(const int* __restrict__ chars, const int* __restrict__ att_type,
                         const int* __restrict__ kw_idx, const float* __restrict__ tblS,
                         const float* __restrict__ fw, const float* __restrict__ fb,
                         const float* __restrict__ gw, const float* __restrict__ gb,
                         const float* __restrict__ mw, const float* __restrict__ mb,
                         const float* __restrict__ kwt, const float* __restrict__ aw,
                         const float* __restrict__ ab, float* __restrict__ x1) {
    int str = blockIdx.x;        // 0..767
    int c = threadIdx.x;         // 0..255
    __shared__ int ch[L_];
    if (c < L_) ch[c] = chars[str * L_ + c];
    __syncthreads();

    int a = str & 3;
    int n = (str >> 2) % N_;
    int sb = str / (N_ * A_);    // s*8+b
    int row = n * 64 + sb * 4 + a;

    float out;
    if (att_type[str] == 1) {
        const float* kr = kwt + kw_idx[str] * EK_;
        const float* awr = aw + c * EK_;
        float acc = ab[c];
        for (int e = 0; e < EK_; ++e) acc += kr[e] * awr[e];
        out = acc;
    } else {
        float xv[L_ + 2];                    // zero-padded embeddings
        xv[0] = 0.f; xv[L_ + 1] = 0.f;
        #pragma unroll
        for (int l = 0; l < L_; ++l) xv[l + 1] = tblS[ch[l] * C_ + c];
        float acc = 0.f;
        #pragma unroll
        for (int o = 0; o < 16; ++o) {
            float f0 = 2.f*fw[o*3], f1 = 2.f*fw[o*3+1], f2 = 2.f*fw[o*3+2], fbv = 2.f*fb[o];
            float g0 = gw[o*3], g1 = gw[o*3+1], g2 = gw[o*3+2], gbv = gb[o];
            float mwv = mw[o];
            float osum = 0.f;
            #pragma unroll
            for (int l = 1; l <= L_; ++l) {
                float xm = xv[l - 1], x0 = xv[l], xp = xv[l + 1];
                float pf2 = fbv + f0 * xm + f1 * x0 + f2 * xp;   // = 2*pf
                float pg  = gbv + g0 * xm + g1 * x0 + g2 * xp;
                pf2 = fminf(fmaxf(pf2, -30.f), 30.f);
                pg  = fminf(fmaxf(pg,  -15.f), 15.f);
                float e1 = __expf(pf2);
                float e2 = __expf(pg);
                float num = (e1 - 1.f) * e2;
                float den = (e1 + 1.f) * (e2 + 1.f);
                osum = fmaf(num, __builtin_amdgcn_rcpf(den), osum);
            }
            acc = fmaf(mwv, osum, acc);
        }
        out = mb[0] + acc * (1.f / 24.f);
    }
    x1[row * C_ + c] = out;
}

// ---------------- GEMM: 64x64 tile, 4x4/thread, double-buffered pipeline ----
#define BM 64
#define BN 64
#define BKT 32
__global__ __launch_bounds__(256, 4)
void gemm64_k(const float* __restrict__ A, const float* __restrict__ W,
              const float* __restrict__ bias, float* __restrict__ C,
              int R, int K, int N, int relu, int kslice) {
    __shared__ float As[2][BKT][BM + 4];
    __shared__ float Bs[2][BKT][BN + 4];
    int tid = threadIdx.x;               // 256
    int tn = tid & 15, tm = tid >> 4;    // 16x16 thread grid
    int row0 = blockIdx.y * BM;
    int col0 = blockIdx.x * BN;
    int kbeg = blockIdx.z * kslice;
    int kend = min(kbeg + kslice, K);
    int nt = (kend - kbeg + BKT - 1) / BKT;

    // loader coords: thread covers tile rows lr0, lr1 at k-offset lk (float4)
    int lr0 = tid >> 3;                  // 0..31
    int lr1 = 32 + lr0;                  // 32..63
    int lk = (tid & 7) * 4;              // 0,4,..,28
    int gr0 = row0 + lr0, gr1 = row0 + lr1;
    int gn0 = col0 + lr0, gn1 = col0 + lr1;
    bool a0ok = gr0 < R, a1ok = gr1 < R;
    bool b0ok = gn0 < N, b1ok = gn1 < N;
    const float* Ar0 = A + (size_t)gr0 * K;
    const float* Ar1 = A + (size_t)gr1 * K;
    const float* Wr0 = W + (size_t)gn0 * K;
    const float* Wr1 = W + (size_t)gn1 * K;

    float acc[4][4];
    #pragma unroll
    for (int i = 0; i < 4; ++i)
        #pragma unroll
        for (int j = 0; j < 4; ++j) acc[i][j] = 0.f;

    float4 va0, va1, vb0, vb1;
    auto gload = [&](int k0) {
        int gk = k0 + lk;
        if (gk + 3 < kend) {            // full granule
            va0 = a0ok ? *(const float4*)(Ar0 + gk) : make_float4(0.f,0.f,0.f,0.f);
            va1 = a1ok ? *(const float4*)(Ar1 + gk) : make_float4(0.f,0.f,0.f,0.f);
            vb0 = b0ok ? *(const float4*)(Wr0 + gk) : make_float4(0.f,0.f,0.f,0.f);
            vb1 = b1ok ? *(const float4*)(Wr1 + gk) : make_float4(0.f,0.f,0.f,0.f);
        } else {
            va0.x = (a0ok && gk+0 < kend) ? Ar0[gk+0] : 0.f;
            va0.y = (a0ok && gk+1 < kend) ? Ar0[gk+1] : 0.f;
            va0.z = (a0ok && gk+2 < kend) ? Ar0[gk+2] : 0.f;
            va0.w = (a0ok && gk+3 < kend) ? Ar0[gk+3] : 0.f;
            va1.x = (a1ok && gk+0 < kend) ? Ar1[gk+0] : 0.f;
            va1.y = (a1ok && gk+1 < kend) ? Ar1[gk+1] : 0.f;
            va1.z = (a1ok && gk+2 < kend) ? Ar1[gk+2] : 0.f;
            va1.w = (a1ok && gk+3 < kend) ? Ar1[gk+3] : 0.f;
            vb0.x = (b0ok && gk+0 < kend) ? Wr0[gk+0] : 0.f;
            vb0.y = (b0ok && gk+1 < kend) ? Wr0[gk+1] : 0.f;
            vb0.z = (b0ok && gk+2 < kend) ? Wr0[gk+2] : 0.f;
            vb0.w = (b0ok && gk+3 < kend) ? Wr0[gk+3] : 0.f;
            vb1.x = (b1ok && gk+0 < kend) ? Wr1[gk+0] : 0.f;
            vb1.y = (b1ok && gk+1 < kend) ? Wr1[gk+1] : 0.f;
            vb1.z = (b1ok && gk+2 < kend) ? Wr1[gk+2] : 0.f;
            vb1.w = (b1ok && gk+3 < kend) ? Wr1[gk+3] : 0.f;
        }
    };
    auto store_lds = [&](int buf) {
        As[buf][lk+0][lr0] = va0.x; As[buf][lk+1][lr0] = va0.y;
        As[buf][lk+2][lr0] = va0.z; As[buf][lk+3][lr0] = va0.w;
        As[buf][lk+0][lr1] = va1.x; As[buf][lk+1][lr1] = va1.y;
        As[buf][lk+2][lr1] = va1.z; As[buf][lk+3][lr1] = va1.w;
        Bs[buf][lk+0][lr0] = vb0.x; Bs[buf][lk+1][lr0] = vb0.y;
        Bs[buf][lk+2][lr0] = vb0.z; Bs[buf][lk+3][lr0] = vb0.w;
        Bs[buf][lk+0][lr1] = vb1.x; Bs[buf][lk+1][lr1] = vb1.y;
        Bs[buf][lk+2][lr1] = vb1.z; Bs[buf][lk+3][lr1] = vb1.w;
    };

    gload(kbeg);
    store_lds(0);
    __syncthreads();
    int cur = 0;
    for (int t = 0; t < nt; ++t) {
        bool more = (t + 1 < nt);
        if (more) gload(kbeg + (t + 1) * BKT);   // issue early; lands during compute
        #pragma unroll
        for (int kk = 0; kk < BKT; ++kk) {
            float4 a4 = *(const float4*)&As[cur][kk][tm * 4];
            float4 b4 = *(const float4*)&Bs[cur][kk][tn * 4];
            acc[0][0] += a4.x * b4.x; acc[0][1] += a4.x * b4.y;
            acc[0][2] += a4.x * b4.z; acc[0][3] += a4.x * b4.w;
            acc[1][0] += a4.y * b4.x; acc[1][1] += a4.y * b4.y;
            acc[1][2] += a4.y * b4.z; acc[1][3] += a4.y * b4.w;
            acc[2][0] += a4.z * b4.x; acc[2][1] += a4.z * b4.y;
            acc[2][2] += a4.z * b4.z; acc[2][3] += a4.z * b4.w;
            acc[3][0] += a4.w * b4.x; acc[3][1] += a4.w * b4.y;
            acc[3][2] += a4.w * b4.z; acc[3][3] += a4.w * b4.w;
        }
        if (more) store_lds(cur ^ 1);
        __syncthreads();
        cur ^= 1;
    }

    bool direct = (gridDim.z == 1);
    float* outp = direct ? C : (C + (size_t)blockIdx.z * R * N);
    int gc = col0 + tn * 4;
    float4 bv = make_float4(0.f, 0.f, 0.f, 0.f);
    if (direct) {
        bv.x = (gc + 0 < N) ? bias[gc + 0] : 0.f;
        bv.y = (gc + 1 < N) ? bias[gc + 1] : 0.f;
        bv.z = (gc + 2 < N) ? bias[gc + 2] : 0.f;
        bv.w = (gc + 3 < N) ? bias[gc + 3] : 0.f;
    }
    #pragma unroll
    for (int mi = 0; mi < 4; ++mi) {
        int gr = row0 + tm * 4 + mi;
        if (gr >= R) continue;
        float4 o;
        o.x = acc[mi][0] + bv.x; o.y = acc[mi][1] + bv.y;
        o.z = acc[mi][2] + bv.z; o.w = acc[mi][3] + bv.w;
        if (direct && relu) {
            o.x = fmaxf(o.x, 0.f); o.y = fmaxf(o.y, 0.f);
            o.z = fmaxf(o.z, 0.f); o.w = fmaxf(o.w, 0.f);
        }
        if (gc + 3 < N) {
            *(float4*)(outp + (size_t)gr * N + gc) = o;
        } else {
            if (gc + 0 < N) outp[(size_t)gr * N + gc + 0] = o.x;
            if (gc + 1 < N) outp[(size_t)gr * N + gc + 1] = o.y;
            if (gc + 2 < N) outp[(size_t)gr * N + gc + 2] = o.z;
            if (gc + 3 < N) outp[(size_t)gr * N + gc + 3] = o.w;
        }
    }
}

// ---------------- attention: one block per batch column j ----------------
__global__ void attn_k(const float* __restrict__ qkv, float* __restrict__ o,
                       int seq, int batch, int d, float scale) {
    __shared__ float sm[3 * 12 * 256];
    __shared__ float sc[12 * 12];
    int j = blockIdx.x, tid = threadIdx.x;
    int sd = seq * d, s3 = 3 * d;
    float* qs = sm;
    float* ks = sm + sd;
    float* vs = sm + 2 * sd;
    for (int idx = tid; idx < sd; idx += 256) {
        int s = idx / d, c = idx - s * d;
        const float* base = qkv + (size_t)(s * batch + j) * s3 + c;
        qs[idx] = base[0];
        ks[idx] = base[d];
        vs[idx] = base[2 * d];
    }
    __syncthreads();
    for (int p = tid; p < seq * seq; p += 256) {
        int s = p / seq, t = p - s * seq;
        float acc = 0.f;
        const float* qp = qs + s * d;
        const float* kp = ks + t * d;
        for (int c = 0; c < d; ++c) acc += qp[c] * kp[c];
        sc[p] = acc * scale;
    }
    __syncthreads();
    if (tid < seq) {
        float m = -1e30f;
        for (int t = 0; t < seq; ++t) m = fmaxf(m, sc[tid * seq + t]);
        float ssum = 0.f;
        for (int t = 0; t < seq; ++t) {
            float e = __expf(sc[tid * seq + t] - m);
            sc[tid * seq + t] = e;
            ssum += e;
        }
        float inv = 1.f / ssum;
        for (int t = 0; t < seq; ++t) sc[tid * seq + t] *= inv;
    }
    __syncthreads();
    for (int c = tid; c < d; c += 256) {
        for (int s = 0; s < seq; ++s) {
            float acc = 0.f;
            for (int t = 0; t < seq; ++t) acc += sc[s * seq + t] * vs[t * d + c];
            o[(size_t)(s * batch + j) * d + c] = acc;
        }
    }
}

// ---------------- fused residual + LayerNorm (in place on x) ----------------
__global__ void add_ln_k(float* __restrict__ x, const float* __restrict__ a,
                         const float* __restrict__ g, const float* __restrict__ b, int d) {
    int r = blockIdx.x, tid = threadIdx.x;
    __shared__ float red[10];
    const float* xr = x + (size_t)r * d;
    const float* ar = a + (size_t)r * d;
    int i0 = tid, i1 = tid + 256;
    bool h0 = i0 < d, h1 = i1 < d;
    float v0 = h0 ? (xr[i0] + ar[i0]) : 0.f;
    float v1 = h1 ? (xr[i1] + ar[i1]) : 0.f;
    float s = v0 + v1, ss = v0 * v0 + v1 * v1;
    for (int off = 32; off; off >>= 1) {
        s += __shfl_down(s, off);
        ss += __shfl_down(ss, off);
    }
    if ((tid & 63) == 0) { red[(tid >> 6) * 2] = s; red[(tid >> 6) * 2 + 1] = ss; }
    __syncthreads();
    if (tid == 0) {
        float S = red[0] + red[2] + red[4] + red[6];
        float SS = red[1] + red[3] + red[5] + red[7];
        float mu = S / d;
        float var = SS / d - mu * mu;
        red[8] = mu;
        red[9] = rsqrtf(var + 1e-5f);
    }
    __syncthreads();
    float mu = red[8], inv = red[9];
    float* xw = x + (size_t)r * d;
    if (h0) xw[i0] = (v0 - mu) * inv * g[i0] + b[i0];
    if (h1) xw[i1] = (v1 - mu) * inv * g[i1] + b[i1];
}

// ------- fused split-K reduce + bias + residual + LayerNorm (in place on x) -
__global__ void redln_k(const float* __restrict__ part, const float* __restrict__ bias,
                        float* __restrict__ x, const float* __restrict__ g,
                        const float* __restrict__ b, int d, int NS, int RN) {
    int r = blockIdx.x, tid = threadIdx.x;
    __shared__ float red[10];
    const float* xr = x + (size_t)r * d;
    int i0 = tid, i1 = tid + 256;
    bool h0 = i0 < d, h1 = i1 < d;
    float v0 = 0.f, v1 = 0.f;
    if (h0) {
        v0 = xr[i0] + bias[i0];
        for (int z = 0; z < NS; ++z) v0 += part[(size_t)z * RN + (size_t)r * d + i0];
    }
    if (h1) {
        v1 = xr[i1] + bias[i1];
        for (int z = 0; z < NS; ++z) v1 += part[(size_t)z * RN + (size_t)r * d + i1];
    }
    float s = v0 + v1, ss = v0 * v0 + v1 * v1;
    for (int off = 32; off; off >>= 1) {
        s += __shfl_down(s, off);
        ss += __shfl_down(ss, off);
    }
    if ((tid & 63) == 0) { red[(tid >> 6) * 2] = s; red[(tid >> 6) * 2 + 1] = ss; }
    __syncthreads();
    if (tid == 0) {
        float S = red[0] + red[2] + red[4] + red[6];
        float SS = red[1] + red[3] + red[5] + red[7];
        float mu = S / d;
        float var = SS / d - mu * mu;
        red[8] = mu;
        red[9] = rsqrtf(var + 1e-5f);
    }
    __syncthreads();
    float mu = red[8], inv = red[9];
    float* xw = x + (size_t)r * d;
    if (h0) xw[i0] = (v0 - mu) * inv * g[i0] + b[i0];
    if (h1) xw[i1] = (v1 - mu) * inv * g[i1] + b[i1];
}

// ---------------- build x2: mean over attrs + concat static ----------------
__global__ void build_x2_k(const float* __restrict__ y1, const float* __restrict__ stat,
                           float* __restrict__ x2) {
    int id = blockIdx.x;                 // 192 blocks
    int n = id % N_;
    int b = (id / N_) % B_;
    int s = id / (N_ * B_);
    int orow = b * (S_ * N_) + s * N_ + n;
    for (int c = threadIdx.x; c < D2_; c += 256) {
        float v;
        if (c < C_) {
            int j0 = (s * B_ + b) * A_;
            float acc = 0.f;
            for (int a = 0; a < A_; ++a) acc += y1[(size_t)(n * 64 + j0 + a) * C_ + c];
            v = acc * 0.25f;
        } else {
            v = stat[((size_t)(s * B_ + b) * N_ + n) * AUX_ + (c - C_)];
        }
        x2[(size_t)orow * D2_ + c] = v;
    }
}

// ---------------- build real: mean over nodes ----------------
__global__ void build_real_k(const float* __restrict__ y2, float* __restrict__ real) {
    int id = blockIdx.x;                 // 16 blocks
    int s = id & 1, b = id >> 1;
    for (int c = threadIdx.x; c < D2_; c += 256) {
        float acc = 0.f;
        for (int n = 0; n < N_; ++n) acc += y2[(size_t)(b * 24 + s * N_ + n) * D2_ + c];
        real[(size_t)(b * 2 + s) * D2_ + c] = acc * (1.f / 12.f);
    }
}

// ---------------- regressor: build feats + 2-layer MLP ----------------
__global__ void regressor_k(const float* __restrict__ real, const int* __restrict__ input_idx,
                            const float* __restrict__ kwt, const float* __restrict__ other,
                            const float* __restrict__ w1, const float* __restrict__ b1,
                            const float* __restrict__ w2, const float* __restrict__ b2,
                            float* __restrict__ out) {
    int b = blockIdx.x;                  // 8
    int tid = threadIdx.x;               // 256
    __shared__ float feats[RIN_];
    __shared__ float hh[32];
    for (int i = tid; i < RIN_; i += 256) {
        float v;
        if (i < 64) {
            float acc = 0.f;
            for (int m = 0; m < M_; ++m) acc += kwt[input_idx[b * M_ + m] * EK_ + i];
            v = acc * 0.125f;
        } else if (i < 336) {
            v = real[(size_t)(b * 2 + 0) * D2_ + (i - 64)];
        } else if (i < 400) {
            int e = i - 336;
            float acc = 0.f;
            for (int m = 0; m < M_; ++m) acc += kwt[input_idx[64 + b * M_ + m] * EK_ + e];
            v = acc * 0.125f;
        } else if (i < 672) {
            v = real[(size_t)(b * 2 + 1) * D2_ + (i - 400)];
        } else {
            v = other[b * 64 + (i - 672)];
        }
        feats[i] = v;
    }
    __syncthreads();
    if (tid < 32) {
        float acc = b1[tid];
        const float* wr = w1 + (size_t)tid * RIN_;
        for (int i = 0; i < RIN_; ++i) acc += feats[i] * wr[i];
        hh[tid] = fmaxf(acc, 0.f);
    }
    __syncthreads();
    if (tid == 0) {
        float acc = b2[0];
        for (int j = 0; j < 32; ++j) acc += hh[j] * w2[j];
        out[b] = acc;
    }
}

// ---------------- host ----------------
extern "C" void kernel_launch(void* const* d_in, const int* in_sizes, int n_in,
                              void* d_out, int out_size, void* d_ws, size_t ws_size,
                              hipStream_t stream) {
    const int*   chars      = (const int*)d_in[0];
    const int*   att_type   = (const int*)d_in[1];
    const int*   kw_idx     = (const int*)d_in[2];
    const int*   input_idx  = (const int*)d_in[3];
    const float* stat       = (const float*)d_in[4];
    const float* other      = (const float*)d_in[5];
    const float* char_table = (const float*)d_in[6];
    const float* filter_w   = (const float*)d_in[7];
    const float* filter_b   = (const float*)d_in[8];
    const float* gate_w     = (const float*)d_in[9];
    const float* gate_b     = (const float*)d_in[10];
    const float* mlp_w      = (const float*)d_in[11];
    const float* mlp_b      = (const float*)d_in[12];
    const float* kw_table   = (const float*)d_in[13];
    const float* aline_w    = (const float*)d_in[14];
    const float* aline_b    = (const float*)d_in[15];
    const float* t1_attn_w  = (const float*)d_in[16];
    const float* t1_attn_b  = (const float*)d_in[17];
    const float* t1_ffn_w1  = (const float*)d_in[18];
    const float* t1_ffn_b1  = (const float*)d_in[19];
    const float* t1_ffn_w2  = (const float*)d_in[20];
    const float* t1_ffn_b2  = (const float*)d_in[21];
    const float* t1_ln_g    = (const float*)d_in[22];
    const float* t1_ln_b    = (const float*)d_in[23];
    const float* t2_attn_w  = (const float*)d_in[24];
    const float* t2_attn_b  = (const float*)d_in[25];
    const float* t2_ffn_w1  = (const float*)d_in[26];
    const float* t2_ffn_b1  = (const float*)d_in[27];
    const float* t2_ffn_w2  = (const float*)d_in[28];
    const float* t2_ffn_b2  = (const float*)d_in[29];
    const float* t2_ln_g    = (const float*)d_in[30];
    const float* t2_ln_b    = (const float*)d_in[31];
    const float* reg_w1     = (const float*)d_in[32];
    const float* reg_b1     = (const float*)d_in[33];
    const float* reg_w2     = (const float*)d_in[34];
    const float* reg_b2     = (const float*)d_in[35];

    float* ws   = (float*)d_ws;
    float* tblS = ws;                    // 32768
    float* x1   = tblS + 32768;          // 768*256  = 196608
    float* qkv  = x1 + 196608;           // 768*768  = 589824
    float* obuf = qkv + 589824;          // 196608  (qkv+obuf contiguous: split-K partials)
    float* abuf = obuf + 196608;         // 196608
    float* hbuf = abuf + 196608;         // 768*2048 = 1572864
    float* x2   = hbuf + 1572864;        // 192*272  = 52224
    float* realb= x2 + 52224;            // 16*272   = 4352
    float* pbuf = qkv;                   // split-K partial region (786432 floats)

    auto gemm = [&](const float* A, const float* W, const float* bias, float* Cc,
                    int R, int K, int N, int relu) {
        dim3 g((N + BN - 1) / BN, (R + BM - 1) / BM, 1);
        gemm64_k<<<g, 256, 0, stream>>>(A, W, bias, Cc, R, K, N, relu, K);
    };
    // split-K GEMM + fused (reduce + bias + residual + LN) into x
    auto gemm_split_ln = [&](const float* A, const float* W, const float* bias, float* x,
                             const float* g, const float* b, int R, int K, int N, int ns) {
        int ksl = ((K + ns - 1) / ns + BKT - 1) / BKT * BKT;
        dim3 gr((N + BN - 1) / BN, (R + BM - 1) / BM, ns);
        gemm64_k<<<gr, 256, 0, stream>>>(A, W, bias, pbuf, R, K, N, 0, ksl);
        redln_k<<<R, 256, 0, stream>>>(pbuf, bias, x, g, b, N, ns, R * N);
    };

    scale_table_k<<<128, 256, 0, stream>>>(char_table, tblS);
    attvec_k<<<NSTR_, 256, 0, stream>>>(chars, att_type, kw_idx, tblS,
                                        filter_w, filter_b, gate_w, gate_b,
                                        mlp_w, mlp_b, kw_table, aline_w, aline_b, x1);

    // ---- transformer 1: seq=12, batch=64, d=256 ----
    for (int i = 0; i < 2; ++i) {
        const float* aw = t1_attn_w + (size_t)i * 4 * C_ * C_;
        const float* ab = t1_attn_b + (size_t)i * 4 * C_;
        gemm(x1, aw, ab, qkv, 768, C_, 3 * C_, 0);
        attn_k<<<64, 256, 0, stream>>>(qkv, obuf, 12, 64, C_, 0.0625f);
        gemm(obuf, aw + 3 * C_ * C_, ab + 3 * C_, abuf, 768, C_, C_, 0);
        add_ln_k<<<768, 256, 0, stream>>>(x1, abuf, t1_ln_g + i * 2 * C_, t1_ln_b + i * 2 * C_, C_);
        gemm(x1, t1_ffn_w1 + (size_t)i * FF_ * C_, t1_ffn_b1 + i * FF_, hbuf, 768, C_, FF_, 1);
        gemm_split_ln(hbuf, t1_ffn_w2 + (size_t)i * C_ * FF_, t1_ffn_b2 + i * C_, x1,
                      t1_ln_g + i * 2 * C_ + C_, t1_ln_b + i * 2 * C_ + C_, 768, FF_, C_, 4);
    }

    build_x2_k<<<192, 256, 0, stream>>>(x1, stat, x2);

    // ---- transformer 2: seq=8, batch=24, d=272 ----
    float sc2 = 1.0f / sqrtf(272.0f);
    for (int i = 0; i < 2; ++i) {
        const float* aw = t2_attn_w + (size_t)i * 4 * D2_ * D2_;
        const float* ab = t2_attn_b + (size_t)i * 4 * D2_;
        gemm(x2, aw, ab, qkv, 192, D2_, 3 * D2_, 0);
        attn_k<<<24, 256, 0, stream>>>(qkv, obuf, 8, 24, D2_, sc2);
        gemm(obuf, aw + 3 * D2_ * D2_, ab + 3 * D2_, abuf, 192, D2_, D2_, 0);
        add_ln_k<<<192, 256, 0, stream>>>(x2, abuf, t2_ln_g + i * 2 * D2_, t2_ln_b + i * 2 * D2_, D2_);
        gemm(x2, t2_ffn_w1 + (size_t)i * FF_ * D2_, t2_ffn_b1 + i * FF_, hbuf, 192, D2_, FF_, 1);
        gemm_split_ln(hbuf, t2_ffn_w2 + (size_t)i * D2_ * FF_, t2_ffn_b2 + i * D2_, x2,
                      t2_ln_g + i * 2 * D2_ + D2_, t2_ln_b + i * 2 * D2_ + D2_, 192, FF_, D2_, 8);
    }

    build_real_k<<<16, 256, 0, stream>>>(x2, realb);
    regressor_k<<<8, 256, 0, stream>>>(realb, input_idx, kw_table, other,
                                       reg_w1, reg_b1, reg_w2, reg_b2, (float*)d_out);
}

// Round 5
// 459.039 us; speedup vs baseline: 5.2687x; 5.2687x over previous
//
#include <hip/hip_runtime.h>
#include <math.h>

// ---------------- constants ----------------
#define S_ 2
#define B_ 8
#define N_ 12
#define A_ 4
#define L_ 24
#define C_ 256
#define AUX_ 16
#define EK_ 64
#define K_ 256
#define M_ 8
#define OTH_ 32
#define D2_ 272
#define FF_ 2048
#define RIN_ 736
#define NSTR_ (S_*B_*N_*A_)   // 768

// ---------------- K0: renorm char table (max_norm=1) ----------------
__global__ void scale_table_k(const float* __restrict__ tbl, float* __restrict__ out) {
    int r = blockIdx.x;          // 128 rows
    int c = threadIdx.x;         // 256
    float v = tbl[r * C_ + c];
    float sq = v * v;
    for (int off = 32; off; off >>= 1) sq += __shfl_down(sq, off);
    __shared__ float red[4];
    __shared__ float scl;
    if ((c & 63) == 0) red[c >> 6] = sq;
    __syncthreads();
    if (c == 0) {
        float n = sqrtf(red[0] + red[1] + red[2] + red[3]);
        scl = fminf(1.f, 1.f / fmaxf(n, 1e-7f));
    }
    __syncthreads();
    out[r * C_ + c] = v * scl;
}

// ---------------- K1: gated conv / keyword path -> x1 layout ----------------
// 512 threads: group 0 handles conv channels 0..7, group 1 handles 8..15
// (keyword path: halves of the 64-wide dot). LDS combine.
__global__ void attvec_k(const int* __restrict__ chars, const int* __restrict__ att_type,
                         const int* __restrict__ kw_idx, const float* __restrict__ tblS,
                         const float* __restrict__ fw, const float* __restrict__ fb,
                         const float* __restrict__ gw, const float* __restrict__ gb,
                         const float* __restrict__ mw, const float* __restrict__ mb,
                         const float* __restrict__ kwt, const float* __restrict__ aw,
                         const float* __restrict__ ab, float* __restrict__ x1) {
    int str = blockIdx.x;        // 0..767
    int tid = threadIdx.x;       // 0..511
    int grp = tid >> 8;          // 0/1
    int c = tid & 255;
    __shared__ int ch[L_];
    __shared__ float part[2][C_];
    if (tid < L_) ch[tid] = chars[str * L_ + tid];
    __syncthreads();

    bool kw = (att_type[str] == 1);
    float partial;
    if (kw) {
        const float* kr = kwt + kw_idx[str] * EK_ + grp * 32;
        const float* awr = aw + c * EK_ + grp * 32;
        float acc = grp ? 0.f : ab[c];
        #pragma unroll
        for (int e = 0; e < 32; ++e) acc = fmaf(kr[e], awr[e], acc);
        partial = acc;
    } else {
        float xv[L_ + 2];                    // zero-padded embeddings
        xv[0] = 0.f; xv[L_ + 1] = 0.f;
        #pragma unroll
        for (int l = 0; l < L_; ++l) xv[l + 1] = tblS[ch[l] * C_ + c];
        float acc = 0.f;
        int obeg = grp * 8;
        #pragma unroll
        for (int oo = 0; oo < 8; ++oo) {
            int o = obeg + oo;
            float f0 = 2.f*fw[o*3], f1 = 2.f*fw[o*3+1], f2 = 2.f*fw[o*3+2], fbv = 2.f*fb[o];
            float g0 = gw[o*3], g1 = gw[o*3+1], g2 = gw[o*3+2], gbv = gb[o];
            float mwv = mw[o];
            float osum = 0.f;
            #pragma unroll
            for (int l = 1; l <= L_; ++l) {
                float xm = xv[l - 1], x0 = xv[l], xp = xv[l + 1];
                float pf2 = fbv + f0 * xm + f1 * x0 + f2 * xp;   // = 2*pf
                float pg  = gbv + g0 * xm + g1 * x0 + g2 * xp;
                pf2 = fminf(fmaxf(pf2, -30.f), 30.f);
                pg  = fminf(fmaxf(pg,  -15.f), 15.f);
                float e1 = __expf(pf2);
                float e2 = __expf(pg);
                float num = (e1 - 1.f) * e2;
                float den = (e1 + 1.f) * (e2 + 1.f);
                osum = fmaf(num, __builtin_amdgcn_rcpf(den), osum);
            }
            acc = fmaf(mwv, osum, acc);
        }
        partial = acc;
    }
    part[grp][c] = partial;
    __syncthreads();
    if (grp == 0) {
        int a = str & 3;
        int n = (str >> 2) % N_;
        int sb = str / (N_ * A_);    // s*8+b
        int row = n * 64 + sb * 4 + a;
        float tot = part[0][c] + part[1][c];
        x1[row * C_ + c] = kw ? tot : (mb[0] + tot * (1.f / 24.f));
    }
}

// ---------------- GEMM: 64x64 tile, 4x4/thread, register prefetch ----------
// Single LDS buffer; loads for tile t+1 issued right after the barrier so
// they complete during compute of tile t. No launch_bounds (R4 lesson:
// capping VGPRs forced the staging regs to scratch -> 100s of MB of spill).
#define BM 64
#define BN 64
#define BKT 32

#define GLOAD(k0) do {                                                        \
    int gk = (k0) + lk;                                                       \
    if (gk + 3 < kend) {                                                      \
        va0 = a0ok ? *(const float4*)(Ar0 + gk) : make_float4(0.f,0.f,0.f,0.f);\
        va1 = a1ok ? *(const float4*)(Ar1 + gk) : make_float4(0.f,0.f,0.f,0.f);\
        vb0 = b0ok ? *(const float4*)(Wr0 + gk) : make_float4(0.f,0.f,0.f,0.f);\
        vb1 = b1ok ? *(const float4*)(Wr1 + gk) : make_float4(0.f,0.f,0.f,0.f);\
    } else {                                                                  \
        va0.x = (a0ok && gk+0 < kend) ? Ar0[gk+0] : 0.f;                      \
        va0.y = (a0ok && gk+1 < kend) ? Ar0[gk+1] : 0.f;                      \
        va0.z = (a0ok && gk+2 < kend) ? Ar0[gk+2] : 0.f;                      \
        va0.w = (a0ok && gk+3 < kend) ? Ar0[gk+3] : 0.f;                      \
        va1.x = (a1ok && gk+0 < kend) ? Ar1[gk+0] : 0.f;                      \
        va1.y = (a1ok && gk+1 < kend) ? Ar1[gk+1] : 0.f;                      \
        va1.z = (a1ok && gk+2 < kend) ? Ar1[gk+2] : 0.f;                      \
        va1.w = (a1ok && gk+3 < kend) ? Ar1[gk+3] : 0.f;                      \
        vb0.x = (b0ok && gk+0 < kend) ? Wr0[gk+0] : 0.f;                      \
        vb0.y = (b0ok && gk+1 < kend) ? Wr0[gk+1] : 0.f;                      \
        vb0.z = (b0ok && gk+2 < kend) ? Wr0[gk+2] : 0.f;                      \
        vb0.w = (b0ok && gk+3 < kend) ? Wr0[gk+3] : 0.f;                      \
        vb1.x = (b1ok && gk+0 < kend) ? Wr1[gk+0] : 0.f;                      \
        vb1.y = (b1ok && gk+1 < kend) ? Wr1[gk+1] : 0.f;                      \
        vb1.z = (b1ok && gk+2 < kend) ? Wr1[gk+2] : 0.f;                      \
        vb1.w = (b1ok && gk+3 < kend) ? Wr1[gk+3] : 0.f;                      \
    }                                                                         \
} while (0)

__global__ void gemm64_k(const float* __restrict__ A, const float* __restrict__ W,
                         const float* __restrict__ bias, float* __restrict__ C,
                         int R, int K, int N, int relu, int kslice) {
    __shared__ float As[BKT][BM + 4];
    __shared__ float Bs[BKT][BN + 4];
    int tid = threadIdx.x;               // 256
    int tn = tid & 15, tm = tid >> 4;    // 16x16 thread grid
    int row0 = blockIdx.y * BM;
    int col0 = blockIdx.x * BN;
    int kbeg = blockIdx.z * kslice;
    int kend = min(kbeg + kslice, K);
    int nt = (kend - kbeg + BKT - 1) / BKT;

    int lr0 = tid >> 3;                  // 0..31
    int lr1 = 32 + lr0;                  // 32..63
    int lk = (tid & 7) * 4;              // 0,4,..,28
    int gr0 = row0 + lr0, gr1 = row0 + lr1;
    int gn0 = col0 + lr0, gn1 = col0 + lr1;
    bool a0ok = gr0 < R, a1ok = gr1 < R;
    bool b0ok = gn0 < N, b1ok = gn1 < N;
    const float* Ar0 = A + (size_t)gr0 * K;
    const float* Ar1 = A + (size_t)gr1 * K;
    const float* Wr0 = W + (size_t)gn0 * K;
    const float* Wr1 = W + (size_t)gn1 * K;

    float acc[4][4];
    #pragma unroll
    for (int i = 0; i < 4; ++i)
        #pragma unroll
        for (int j = 0; j < 4; ++j) acc[i][j] = 0.f;

    float4 va0, va1, vb0, vb1;
    GLOAD(kbeg);                          // prologue load, tile 0
    for (int t = 0; t < nt; ++t) {
        // commit staged registers to LDS (transposed: [k][row])
        As[lk+0][lr0] = va0.x; As[lk+1][lr0] = va0.y;
        As[lk+2][lr0] = va0.z; As[lk+3][lr0] = va0.w;
        As[lk+0][lr1] = va1.x; As[lk+1][lr1] = va1.y;
        As[lk+2][lr1] = va1.z; As[lk+3][lr1] = va1.w;
        Bs[lk+0][lr0] = vb0.x; Bs[lk+1][lr0] = vb0.y;
        Bs[lk+2][lr0] = vb0.z; Bs[lk+3][lr0] = vb0.w;
        Bs[lk+0][lr1] = vb1.x; Bs[lk+1][lr1] = vb1.y;
        Bs[lk+2][lr1] = vb1.z; Bs[lk+3][lr1] = vb1.w;
        __syncthreads();
        if (t + 1 < nt) GLOAD(kbeg + (t + 1) * BKT);   // lands during compute
        #pragma unroll
        for (int kk = 0; kk < BKT; ++kk) {
            float4 a4 = *(const float4*)&As[kk][tm * 4];
            float4 b4 = *(const float4*)&Bs[kk][tn * 4];
            acc[0][0] += a4.x * b4.x; acc[0][1] += a4.x * b4.y;
            acc[0][2] += a4.x * b4.z; acc[0][3] += a4.x * b4.w;
            acc[1][0] += a4.y * b4.x; acc[1][1] += a4.y * b4.y;
            acc[1][2] += a4.y * b4.z; acc[1][3] += a4.y * b4.w;
            acc[2][0] += a4.z * b4.x; acc[2][1] += a4.z * b4.y;
            acc[2][2] += a4.z * b4.z; acc[2][3] += a4.z * b4.w;
            acc[3][0] += a4.w * b4.x; acc[3][1] += a4.w * b4.y;
            acc[3][2] += a4.w * b4.z; acc[3][3] += a4.w * b4.w;
        }
        __syncthreads();
    }

    bool direct = (gridDim.z == 1);
    float* outp = direct ? C : (C + (size_t)blockIdx.z * R * N);
    int gc = col0 + tn * 4;
    float4 bv = make_float4(0.f, 0.f, 0.f, 0.f);
    if (direct) {
        bv.x = (gc + 0 < N) ? bias[gc + 0] : 0.f;
        bv.y = (gc + 1 < N) ? bias[gc + 1] : 0.f;
        bv.z = (gc + 2 < N) ? bias[gc + 2] : 0.f;
        bv.w = (gc + 3 < N) ? bias[gc + 3] : 0.f;
    }
    #pragma unroll
    for (int mi = 0; mi < 4; ++mi) {
        int gr = row0 + tm * 4 + mi;
        if (gr >= R) continue;
        float4 o;
        o.x = acc[mi][0] + bv.x; o.y = acc[mi][1] + bv.y;
        o.z = acc[mi][2] + bv.z; o.w = acc[mi][3] + bv.w;
        if (direct && relu) {
            o.x = fmaxf(o.x, 0.f); o.y = fmaxf(o.y, 0.f);
            o.z = fmaxf(o.z, 0.f); o.w = fmaxf(o.w, 0.f);
        }
        if (gc + 3 < N) {
            *(float4*)(outp + (size_t)gr * N + gc) = o;
        } else {
            if (gc + 0 < N) outp[(size_t)gr * N + gc + 0] = o.x;
            if (gc + 1 < N) outp[(size_t)gr * N + gc + 1] = o.y;
            if (gc + 2 < N) outp[(size_t)gr * N + gc + 2] = o.z;
            if (gc + 3 < N) outp[(size_t)gr * N + gc + 3] = o.w;
        }
    }
}

// ---------------- attention: one block per batch column j ----------------
__global__ void attn_k(const float* __restrict__ qkv, float* __restrict__ o,
                       int seq, int batch, int d, float scale) {
    __shared__ float sm[3 * 12 * 256];
    __shared__ float sc[12 * 12];
    int j = blockIdx.x, tid = threadIdx.x;
    int sd = seq * d, s3 = 3 * d;
    float* qs = sm;
    float* ks = sm + sd;
    float* vs = sm + 2 * sd;
    for (int idx = tid; idx < sd; idx += 256) {
        int s = idx / d, c = idx - s * d;
        const float* base = qkv + (size_t)(s * batch + j) * s3 + c;
        qs[idx] = base[0];
        ks[idx] = base[d];
        vs[idx] = base[2 * d];
    }
    __syncthreads();
    for (int p = tid; p < seq * seq; p += 256) {
        int s = p / seq, t = p - s * seq;
        float acc = 0.f;
        const float* qp = qs + s * d;
        const float* kp = ks + t * d;
        for (int c = 0; c < d; ++c) acc += qp[c] * kp[c];
        sc[p] = acc * scale;
    }
    __syncthreads();
    if (tid < seq) {
        float m = -1e30f;
        for (int t = 0; t < seq; ++t) m = fmaxf(m, sc[tid * seq + t]);
        float ssum = 0.f;
        for (int t = 0; t < seq; ++t) {
            float e = __expf(sc[tid * seq + t] - m);
            sc[tid * seq + t] = e;
            ssum += e;
        }
        float inv = 1.f / ssum;
        for (int t = 0; t < seq; ++t) sc[tid * seq + t] *= inv;
    }
    __syncthreads();
    for (int c = tid; c < d; c += 256) {
        for (int s = 0; s < seq; ++s) {
            float acc = 0.f;
            for (int t = 0; t < seq; ++t) acc += sc[s * seq + t] * vs[t * d + c];
            o[(size_t)(s * batch + j) * d + c] = acc;
        }
    }
}

// ---------------- fused residual + LayerNorm (in place on x) ----------------
__global__ void add_ln_k(float* __restrict__ x, const float* __restrict__ a,
                         const float* __restrict__ g, const float* __restrict__ b, int d) {
    int r = blockIdx.x, tid = threadIdx.x;
    __shared__ float red[10];
    const float* xr = x + (size_t)r * d;
    const float* ar = a + (size_t)r * d;
    int i0 = tid, i1 = tid + 256;
    bool h0 = i0 < d, h1 = i1 < d;
    float v0 = h0 ? (xr[i0] + ar[i0]) : 0.f;
    float v1 = h1 ? (xr[i1] + ar[i1]) : 0.f;
    float s = v0 + v1, ss = v0 * v0 + v1 * v1;
    for (int off = 32; off; off >>= 1) {
        s += __shfl_down(s, off);
        ss += __shfl_down(ss, off);
    }
    if ((tid & 63) == 0) { red[(tid >> 6) * 2] = s; red[(tid >> 6) * 2 + 1] = ss; }
    __syncthreads();
    if (tid == 0) {
        float S = red[0] + red[2] + red[4] + red[6];
        float SS = red[1] + red[3] + red[5] + red[7];
        float mu = S / d;
        float var = SS / d - mu * mu;
        red[8] = mu;
        red[9] = rsqrtf(var + 1e-5f);
    }
    __syncthreads();
    float mu = red[8], inv = red[9];
    float* xw = x + (size_t)r * d;
    if (h0) xw[i0] = (v0 - mu) * inv * g[i0] + b[i0];
    if (h1) xw[i1] = (v1 - mu) * inv * g[i1] + b[i1];
}

// ------- fused split-K reduce + bias + residual + LayerNorm (in place on x) -
__global__ void redln_k(const float* __restrict__ part, const float* __restrict__ bias,
                        float* __restrict__ x, const float* __restrict__ g,
                        const float* __restrict__ b, int d, int NS, int RN) {
    int r = blockIdx.x, tid = threadIdx.x;
    __shared__ float red[10];
    const float* xr = x + (size_t)r * d;
    int i0 = tid, i1 = tid + 256;
    bool h0 = i0 < d, h1 = i1 < d;
    float v0 = 0.f, v1 = 0.f;
    if (h0) {
        v0 = xr[i0] + bias[i0];
        for (int z = 0; z < NS; ++z) v0 += part[(size_t)z * RN + (size_t)r * d + i0];
    }
    if (h1) {
        v1 = xr[i1] + bias[i1];
        for (int z = 0; z < NS; ++z) v1 += part[(size_t)z * RN + (size_t)r * d + i1];
    }
    float s = v0 + v1, ss = v0 * v0 + v1 * v1;
    for (int off = 32; off; off >>= 1) {
        s += __shfl_down(s, off);
        ss += __shfl_down(ss, off);
    }
    if ((tid & 63) == 0) { red[(tid >> 6) * 2] = s; red[(tid >> 6) * 2 + 1] = ss; }
    __syncthreads();
    if (tid == 0) {
        float S = red[0] + red[2] + red[4] + red[6];
        float SS = red[1] + red[3] + red[5] + red[7];
        float mu = S / d;
        float var = SS / d - mu * mu;
        red[8] = mu;
        red[9] = rsqrtf(var + 1e-5f);
    }
    __syncthreads();
    float mu = red[8], inv = red[9];
    float* xw = x + (size_t)r * d;
    if (h0) xw[i0] = (v0 - mu) * inv * g[i0] + b[i0];
    if (h1) xw[i1] = (v1 - mu) * inv * g[i1] + b[i1];
}

// ---------------- build x2: mean over attrs + concat static ----------------
__global__ void build_x2_k(const float* __restrict__ y1, const float* __restrict__ stat,
                           float* __restrict__ x2) {
    int id = blockIdx.x;                 // 192 blocks
    int n = id % N_;
    int b = (id / N_) % B_;
    int s = id / (N_ * B_);
    int orow = b * (S_ * N_) + s * N_ + n;
    for (int c = threadIdx.x; c < D2_; c += 256) {
        float v;
        if (c < C_) {
            int j0 = (s * B_ + b) * A_;
            float acc = 0.f;
            for (int a = 0; a < A_; ++a) acc += y1[(size_t)(n * 64 + j0 + a) * C_ + c];
            v = acc * 0.25f;
        } else {
            v = stat[((size_t)(s * B_ + b) * N_ + n) * AUX_ + (c - C_)];
        }
        x2[(size_t)orow * D2_ + c] = v;
    }
}

// ---------------- build real: mean over nodes ----------------
__global__ void build_real_k(const float* __restrict__ y2, float* __restrict__ real) {
    int id = blockIdx.x;                 // 16 blocks
    int s = id & 1, b = id >> 1;
    for (int c = threadIdx.x; c < D2_; c += 256) {
        float acc = 0.f;
        for (int n = 0; n < N_; ++n) acc += y2[(size_t)(b * 24 + s * N_ + n) * D2_ + c];
        real[(size_t)(b * 2 + s) * D2_ + c] = acc * (1.f / 12.f);
    }
}

// ---------------- regressor: build feats + 2-layer MLP ----------------
__global__ void regressor_k(const float* __restrict__ real, const int* __restrict__ input_idx,
                            const float* __restrict__ kwt, const float* __restrict__ other,
                            const float* __restrict__ w1, const float* __restrict__ b1,
                            const float* __restrict__ w2, const float* __restrict__ b2,
                            float* __restrict__ out) {
    int b = blockIdx.x;                  // 8
    int tid = threadIdx.x;               // 256
    __shared__ float feats[RIN_];
    __shared__ float hh[32];
    for (int i = tid; i < RIN_; i += 256) {
        float v;
        if (i < 64) {
            float acc = 0.f;
            for (int m = 0; m < M_; ++m) acc += kwt[input_idx[b * M_ + m] * EK_ + i];
            v = acc * 0.125f;
        } else if (i < 336) {
            v = real[(size_t)(b * 2 + 0) * D2_ + (i - 64)];
        } else if (i < 400) {
            int e = i - 336;
            float acc = 0.f;
            for (int m = 0; m < M_; ++m) acc += kwt[input_idx[64 + b * M_ + m] * EK_ + e];
            v = acc * 0.125f;
        } else if (i < 672) {
            v = real[(size_t)(b * 2 + 1) * D2_ + (i - 400)];
        } else {
            v = other[b * 64 + (i - 672)];
        }
        feats[i] = v;
    }
    __syncthreads();
    if (tid < 32) {
        float acc = b1[tid];
        const float* wr = w1 + (size_t)tid * RIN_;
        for (int i = 0; i < RIN_; ++i) acc += feats[i] * wr[i];
        hh[tid] = fmaxf(acc, 0.f);
    }
    __syncthreads();
    if (tid == 0) {
        float acc = b2[0];
        for (int j = 0; j < 32; ++j) acc += hh[j] * w2[j];
        out[b] = acc;
    }
}

// ---------------- host ----------------
extern "C" void kernel_launch(void* const* d_in, const int* in_sizes, int n_in,
                              void* d_out, int out_size, void* d_ws, size_t ws_size,
                              hipStream_t stream) {
    const int*   chars      = (const int*)d_in[0];
    const int*   att_type   = (const int*)d_in[1];
    const int*   kw_idx     = (const int*)d_in[2];
    const int*   input_idx  = (const int*)d_in[3];
    const float* stat       = (const float*)d_in[4];
    const float* other      = (const float*)d_in[5];
    const float* char_table = (const float*)d_in[6];
    const float* filter_w   = (const float*)d_in[7];
    const float* filter_b   = (const float*)d_in[8];
    const float* gate_w     = (const float*)d_in[9];
    const float* gate_b     = (const float*)d_in[10];
    const float* mlp_w      = (const float*)d_in[11];
    const float* mlp_b      = (const float*)d_in[12];
    const float* kw_table   = (const float*)d_in[13];
    const float* aline_w    = (const float*)d_in[14];
    const float* aline_b    = (const float*)d_in[15];
    const float* t1_attn_w  = (const float*)d_in[16];
    const float* t1_attn_b  = (const float*)d_in[17];
    const float* t1_ffn_w1  = (const float*)d_in[18];
    const float* t1_ffn_b1  = (const float*)d_in[19];
    const float* t1_ffn_w2  = (const float*)d_in[20];
    const float* t1_ffn_b2  = (const float*)d_in[21];
    const float* t1_ln_g    = (const float*)d_in[22];
    const float* t1_ln_b    = (const float*)d_in[23];
    const float* t2_attn_w  = (const float*)d_in[24];
    const float* t2_attn_b  = (const float*)d_in[25];
    const float* t2_ffn_w1  = (const float*)d_in[26];
    const float* t2_ffn_b1  = (const float*)d_in[27];
    const float* t2_ffn_w2  = (const float*)d_in[28];
    const float* t2_ffn_b2  = (const float*)d_in[29];
    const float* t2_ln_g    = (const float*)d_in[30];
    const float* t2_ln_b    = (const float*)d_in[31];
    const float* reg_w1     = (const float*)d_in[32];
    const float* reg_b1     = (const float*)d_in[33];
    const float* reg_w2     = (const float*)d_in[34];
    const float* reg_b2     = (const float*)d_in[35];

    float* ws   = (float*)d_ws;
    float* tblS = ws;                    // 32768
    float* x1   = tblS + 32768;          // 768*256  = 196608
    float* qkv  = x1 + 196608;           // 768*768  = 589824
    float* obuf = qkv + 589824;          // 196608  (qkv+obuf contiguous: split-K partials)
    float* abuf = obuf + 196608;         // 196608
    float* hbuf = abuf + 196608;         // 768*2048 = 1572864
    float* x2   = hbuf + 1572864;        // 192*272  = 52224
    float* realb= x2 + 52224;            // 16*272   = 4352
    float* pbuf = qkv;                   // split-K partial region (786432 floats)

    auto gemm = [&](const float* A, const float* W, const float* bias, float* Cc,
                    int R, int K, int N, int relu) {
        dim3 g((N + BN - 1) / BN, (R + BM - 1) / BM, 1);
        gemm64_k<<<g, 256, 0, stream>>>(A, W, bias, Cc, R, K, N, relu, K);
    };
    // split-K GEMM + fused (reduce + bias + residual + LN) into x
    auto gemm_split_ln = [&](const float* A, const float* W, const float* bias, float* x,
                             const float* g, const float* b, int R, int K, int N, int ns) {
        int ksl = ((K + ns - 1) / ns + BKT - 1) / BKT * BKT;
        dim3 gr((N + BN - 1) / BN, (R + BM - 1) / BM, ns);
        gemm64_k<<<gr, 256, 0, stream>>>(A, W, bias, pbuf, R, K, N, 0, ksl);
        redln_k<<<R, 256, 0, stream>>>(pbuf, bias, x, g, b, N, ns, R * N);
    };

    scale_table_k<<<128, 256, 0, stream>>>(char_table, tblS);
    attvec_k<<<NSTR_, 512, 0, stream>>>(chars, att_type, kw_idx, tblS,
                                        filter_w, filter_b, gate_w, gate_b,
                                        mlp_w, mlp_b, kw_table, aline_w, aline_b, x1);

    // ---- transformer 1: seq=12, batch=64, d=256 ----
    for (int i = 0; i < 2; ++i) {
        const float* aw = t1_attn_w + (size_t)i * 4 * C_ * C_;
        const float* ab = t1_attn_b + (size_t)i * 4 * C_;
        gemm(x1, aw, ab, qkv, 768, C_, 3 * C_, 0);
        attn_k<<<64, 256, 0, stream>>>(qkv, obuf, 12, 64, C_, 0.0625f);
        gemm(obuf, aw + 3 * C_ * C_, ab + 3 * C_, abuf, 768, C_, C_, 0);
        add_ln_k<<<768, 256, 0, stream>>>(x1, abuf, t1_ln_g + i * 2 * C_, t1_ln_b + i * 2 * C_, C_);
        gemm(x1, t1_ffn_w1 + (size_t)i * FF_ * C_, t1_ffn_b1 + i * FF_, hbuf, 768, C_, FF_, 1);
        gemm_split_ln(hbuf, t1_ffn_w2 + (size_t)i * C_ * FF_, t1_ffn_b2 + i * C_, x1,
                      t1_ln_g + i * 2 * C_ + C_, t1_ln_b + i * 2 * C_ + C_, 768, FF_, C_, 4);
    }

    build_x2_k<<<192, 256, 0, stream>>>(x1, stat, x2);

    // ---- transformer 2: seq=8, batch=24, d=272 ----
    float sc2 = 1.0f / sqrtf(272.0f);
    for (int i = 0; i < 2; ++i) {
        const float* aw = t2_attn_w + (size_t)i * 4 * D2_ * D2_;
        const float* ab = t2_attn_b + (size_t)i * 4 * D2_;
        gemm(x2, aw, ab, qkv, 192, D2_, 3 * D2_, 0);
        attn_k<<<24, 256, 0, stream>>>(qkv, obuf, 8, 24, D2_, sc2);
        gemm(obuf, aw + 3 * D2_ * D2_, ab + 3 * D2_, abuf, 192, D2_, D2_, 0);
        add_ln_k<<<192, 256, 0, stream>>>(x2, abuf, t2_ln_g + i * 2 * D2_, t2_ln_b + i * 2 * D2_, D2_);
        gemm(x2, t2_ffn_w1 + (size_t)i * FF_ * D2_, t2_ffn_b1 + i * FF_, hbuf, 192, D2_, FF_, 1);
        gemm_split_ln(hbuf, t2_ffn_w2 + (size_t)i * D2_ * FF_, t2_ffn_b2 + i * D2_, x2,
                      t2_ln_g + i * 2 * D2_ + D2_, t2_ln_b + i * 2 * D2_ + D2_, 192, FF_, D2_, 8);
    }

    build_real_k<<<16, 256, 0, stream>>>(x2, realb);
    regressor_k<<<8, 256, 0, stream>>>(realb, input_idx, kw_table, other,
                                       reg_w1, reg_b1, reg_w2, reg_b2, (float*)d_out);
}

// Round 6
// 434.320 us; speedup vs baseline: 5.5686x; 1.0569x over previous
//
#include <hip/hip_runtime.h>
#include <math.h>

// ---------------- constants ----------------
#define S_ 2
#define B_ 8
#define N_ 12
#define A_ 4
#define L_ 24
#define C_ 256
#define AUX_ 16
#define EK_ 64
#define K_ 256
#define M_ 8
#define OTH_ 32
#define D2_ 272
#define FF_ 2048
#define RIN_ 736
#define NSTR_ (S_*B_*N_*A_)   // 768

typedef __attribute__((ext_vector_type(8))) short short8v;   // bf16x8 MFMA frag
typedef __attribute__((ext_vector_type(4))) float f32x4;     // MFMA acc

__device__ __forceinline__ unsigned cvt_pk_bf16(float a, float b) {
    unsigned r;
    asm("v_cvt_pk_bf16_f32 %0, %1, %2" : "=v"(r) : "v"(a), "v"(b));
    return r;
}
__device__ __forceinline__ unsigned short f2bf(float f) {     // RNE f32->bf16
    unsigned u = __float_as_uint(f);
    return (unsigned short)((u + 0x7FFFu + ((u >> 16) & 1u)) >> 16);
}

// ---------------- weight conversion: 6 segments -> contiguous bf16 ----------
// offsets (elements): t1_attn 0, t1_ffn1 524288, t1_ffn2 1572864,
// t2_attn 2621440, t2_ffn1 3213312, t2_ffn2 4327424, total 5441536
__global__ void cvt_w_k(const float* __restrict__ s0, const float* __restrict__ s1,
                        const float* __restrict__ s2, const float* __restrict__ s3,
                        const float* __restrict__ s4, const float* __restrict__ s5,
                        unsigned short* __restrict__ dst) {
    const int T = 5441536 / 4;
    for (int q = blockIdx.x * 256 + threadIdx.x; q < T; q += gridDim.x * 256) {
        int idx = q * 4;
        const float* src; int off;
        if      (idx < 524288)  { src = s0; off = 0; }
        else if (idx < 1572864) { src = s1; off = 524288; }
        else if (idx < 2621440) { src = s2; off = 1572864; }
        else if (idx < 3213312) { src = s3; off = 2621440; }
        else if (idx < 4327424) { src = s4; off = 3213312; }
        else                    { src = s5; off = 4327424; }
        float4 v = *(const float4*)(src + (idx - off));
        ushort4 o;
        o.x = f2bf(v.x); o.y = f2bf(v.y); o.z = f2bf(v.z); o.w = f2bf(v.w);
        *(ushort4*)(dst + idx) = o;
    }
}

// ---------------- K0: renorm char table (max_norm=1) ----------------
__global__ void scale_table_k(const float* __restrict__ tbl, float* __restrict__ out) {
    int r = blockIdx.x;          // 128 rows
    int c = threadIdx.x;         // 256
    float v = tbl[r * C_ + c];
    float sq = v * v;
    for (int off = 32; off; off >>= 1) sq += __shfl_down(sq, off);
    __shared__ float red[4];
    __shared__ float scl;
    if ((c & 63) == 0) red[c >> 6] = sq;
    __syncthreads();
    if (c == 0) {
        float n = sqrtf(red[0] + red[1] + red[2] + red[3]);
        scl = fminf(1.f, 1.f / fmaxf(n, 1e-7f));
    }
    __syncthreads();
    out[r * C_ + c] = v * scl;
}

// ---------------- K1: gated conv / keyword path -> x1 layout ----------------
__global__ void attvec_k(const int* __restrict__ chars, const int* __restrict__ att_type,
                         const int* __restrict__ kw_idx, const float* __restrict__ tblS,
                         const float* __restrict__ fw, const float* __restrict__ fb,
                         const float* __restrict__ gw, const float* __restrict__ gb,
                         const float* __restrict__ mw, const float* __restrict__ mb,
                         const float* __restrict__ kwt, const float* __restrict__ aw,
                         const float* __restrict__ ab, float* __restrict__ x1) {
    int str = blockIdx.x;        // 0..767
    int tid = threadIdx.x;       // 0..511
    int grp = tid >> 8;          // 0/1
    int c = tid & 255;
    __shared__ int ch[L_];
    __shared__ float part[2][C_];
    if (tid < L_) ch[tid] = chars[str * L_ + tid];
    __syncthreads();

    bool kw = (att_type[str] == 1);
    float partial;
    if (kw) {
        const float* kr = kwt + kw_idx[str] * EK_ + grp * 32;
        const float* awr = aw + c * EK_ + grp * 32;
        float acc = grp ? 0.f : ab[c];
        #pragma unroll
        for (int e = 0; e < 32; ++e) acc = fmaf(kr[e], awr[e], acc);
        partial = acc;
    } else {
        float xv[L_ + 2];
        xv[0] = 0.f; xv[L_ + 1] = 0.f;
        #pragma unroll
        for (int l = 0; l < L_; ++l) xv[l + 1] = tblS[ch[l] * C_ + c];
        float acc = 0.f;
        int obeg = grp * 8;
        #pragma unroll
        for (int oo = 0; oo < 8; ++oo) {
            int o = obeg + oo;
            float f0 = 2.f*fw[o*3], f1 = 2.f*fw[o*3+1], f2 = 2.f*fw[o*3+2], fbv = 2.f*fb[o];
            float g0 = gw[o*3], g1 = gw[o*3+1], g2 = gw[o*3+2], gbv = gb[o];
            float mwv = mw[o];
            float osum = 0.f;
            #pragma unroll
            for (int l = 1; l <= L_; ++l) {
                float xm = xv[l - 1], x0 = xv[l], xp = xv[l + 1];
                float pf2 = fbv + f0 * xm + f1 * x0 + f2 * xp;   // = 2*pf
                float pg  = gbv + g0 * xm + g1 * x0 + g2 * xp;
                pf2 = fminf(fmaxf(pf2, -30.f), 30.f);
                pg  = fminf(fmaxf(pg,  -15.f), 15.f);
                float e1 = __expf(pf2);
                float e2 = __expf(pg);
                float num = (e1 - 1.f) * e2;
                float den = (e1 + 1.f) * (e2 + 1.f);
                osum = fmaf(num, __builtin_amdgcn_rcpf(den), osum);
            }
            acc = fmaf(mwv, osum, acc);
        }
        partial = acc;
    }
    part[grp][c] = partial;
    __syncthreads();
    if (grp == 0) {
        int a = str & 3;
        int n = (str >> 2) % N_;
        int sb = str / (N_ * A_);
        int row = n * 64 + sb * 4 + a;
        float tot = part[0][c] + part[1][c];
        x1[row * C_ + c] = kw ? tot : (mb[0] + tot * (1.f / 24.f));
    }
}

// ---------------- MFMA GEMM: C[r,n] = A[r,:](f32) . Wb[n,:](bf16) ----------
// 64x64 tile / block, 4 waves x (64m x 16n). A converted to bf16 in-register.
// mfma_f32_16x16x32_bf16: A lane: row=lane&15, k=8*(lane>>4)+j (k-contig 16B)
//                         B lane: col=lane&15, same k      (verified m89/m91)
//                         D lane: col=lane&15, row=4*(lane>>4)+j
// Requires R % 64 == 0 (true for 768/192). N, K tails guarded.
__global__ void gemm_mfma_k(const float* __restrict__ A, const unsigned short* __restrict__ Wb,
                            const float* __restrict__ bias, float* __restrict__ C,
                            int R, int K, int N, int relu, int kslice) {
    int tid = threadIdx.x;
    int wave = tid >> 6, lane = tid & 63;
    int fr = lane & 15, fq = lane >> 4;
    int m0 = blockIdx.y * 64;
    int n0 = blockIdx.x * 64 + wave * 16;
    int kbeg = blockIdx.z * kslice;
    int kend = min(kbeg + kslice, K);
    int col = n0 + fr;
    bool bok = col < N;
    const unsigned short* Wrow = Wb + (size_t)col * K;

    f32x4 acc0 = {0.f,0.f,0.f,0.f}, acc1 = {0.f,0.f,0.f,0.f};
    f32x4 acc2 = {0.f,0.f,0.f,0.f}, acc3 = {0.f,0.f,0.f,0.f};
    const short8v z8 = {0,0,0,0,0,0,0,0};

    for (int kt = kbeg; kt < kend; kt += 32) {
        int kl = kt + fq * 8;
        bool kv = (kl + 8 <= kend);           // K divisible by 8 in all calls
        short8v bf = (bok && kv) ? *(const short8v*)(Wrow + kl) : z8;
        short8v af0, af1, af2, af3;
#define LOADA(dst, mi) do {                                               \
        if (kv) {                                                         \
            const float* ap = A + (size_t)(m0 + (mi)*16 + fr) * K + kl;   \
            float4 x0 = *(const float4*)ap;                               \
            float4 x1 = *(const float4*)(ap + 4);                         \
            union { unsigned u[4]; short8v s; } cvu;                      \
            cvu.u[0] = cvt_pk_bf16(x0.x, x0.y);                           \
            cvu.u[1] = cvt_pk_bf16(x0.z, x0.w);                           \
            cvu.u[2] = cvt_pk_bf16(x1.x, x1.y);                           \
            cvu.u[3] = cvt_pk_bf16(x1.z, x1.w);                           \
            dst = cvu.s;                                                  \
        } else dst = z8;                                                  \
    } while (0)
        LOADA(af0, 0); LOADA(af1, 1); LOADA(af2, 2); LOADA(af3, 3);
#undef LOADA
        acc0 = __builtin_amdgcn_mfma_f32_16x16x32_bf16(af0, bf, acc0, 0, 0, 0);
        acc1 = __builtin_amdgcn_mfma_f32_16x16x32_bf16(af1, bf, acc1, 0, 0, 0);
        acc2 = __builtin_amdgcn_mfma_f32_16x16x32_bf16(af2, bf, acc2, 0, 0, 0);
        acc3 = __builtin_amdgcn_mfma_f32_16x16x32_bf16(af3, bf, acc3, 0, 0, 0);
    }

    if (!bok) return;
    bool direct = (gridDim.z == 1);
    float* outp = direct ? C : (C + (size_t)blockIdx.z * R * N);
    float bv = direct ? bias[col] : 0.f;
#define STOREACC(accv, mi) do {                                           \
        _Pragma("unroll")                                                 \
        for (int j = 0; j < 4; ++j) {                                     \
            int row = m0 + (mi)*16 + fq * 4 + j;                          \
            float v = accv[j] + bv;                                       \
            if (direct && relu) v = fmaxf(v, 0.f);                        \
            outp[(size_t)row * N + col] = v;                              \
        }                                                                 \
    } while (0)
    STOREACC(acc0, 0); STOREACC(acc1, 1); STOREACC(acc2, 2); STOREACC(acc3, 3);
#undef STOREACC
}

// ---------------- attention: one block per batch column j ----------------
__global__ void attn_k(const float* __restrict__ qkv, float* __restrict__ o,
                       int seq, int batch, int d, float scale) {
    __shared__ float sm[3 * 12 * 256];
    __shared__ float sc[12 * 12];
    int j = blockIdx.x, tid = threadIdx.x;
    int sd = seq * d, s3 = 3 * d;
    float* qs = sm;
    float* ks = sm + sd;
    float* vs = sm + 2 * sd;
    for (int idx = tid; idx < sd; idx += 256) {
        int s = idx / d, c = idx - s * d;
        const float* base = qkv + (size_t)(s * batch + j) * s3 + c;
        qs[idx] = base[0];
        ks[idx] = base[d];
        vs[idx] = base[2 * d];
    }
    __syncthreads();
    for (int p = tid; p < seq * seq; p += 256) {
        int s = p / seq, t = p - s * seq;
        float acc = 0.f;
        const float* qp = qs + s * d;
        const float* kp = ks + t * d;
        for (int c = 0; c < d; ++c) acc += qp[c] * kp[c];
        sc[p] = acc * scale;
    }
    __syncthreads();
    if (tid < seq) {
        float m = -1e30f;
        for (int t = 0; t < seq; ++t) m = fmaxf(m, sc[tid * seq + t]);
        float ssum = 0.f;
        for (int t = 0; t < seq; ++t) {
            float e = __expf(sc[tid * seq + t] - m);
            sc[tid * seq + t] = e;
            ssum += e;
        }
        float inv = 1.f / ssum;
        for (int t = 0; t < seq; ++t) sc[tid * seq + t] *= inv;
    }
    __syncthreads();
    for (int c = tid; c < d; c += 256) {
        for (int s = 0; s < seq; ++s) {
            float acc = 0.f;
            for (int t = 0; t < seq; ++t) acc += sc[s * seq + t] * vs[t * d + c];
            o[(size_t)(s * batch + j) * d + c] = acc;
        }
    }
}

// ------- fused split-K reduce + bias + residual + LayerNorm (in place on x) -
__global__ void redln_k(const float* __restrict__ part, const float* __restrict__ bias,
                        float* __restrict__ x, const float* __restrict__ g,
                        const float* __restrict__ b, int d, int NS, int RN) {
    int r = blockIdx.x, tid = threadIdx.x;
    __shared__ float red[10];
    const float* xr = x + (size_t)r * d;
    int i0 = tid, i1 = tid + 256;
    bool h0 = i0 < d, h1 = i1 < d;
    float v0 = 0.f, v1 = 0.f;
    if (h0) {
        v0 = xr[i0] + bias[i0];
        for (int z = 0; z < NS; ++z) v0 += part[(size_t)z * RN + (size_t)r * d + i0];
    }
    if (h1) {
        v1 = xr[i1] + bias[i1];
        for (int z = 0; z < NS; ++z) v1 += part[(size_t)z * RN + (size_t)r * d + i1];
    }
    float s = v0 + v1, ss = v0 * v0 + v1 * v1;
    for (int off = 32; off; off >>= 1) {
        s += __shfl_down(s, off);
        ss += __shfl_down(ss, off);
    }
    if ((tid & 63) == 0) { red[(tid >> 6) * 2] = s; red[(tid >> 6) * 2 + 1] = ss; }
    __syncthreads();
    if (tid == 0) {
        float S = red[0] + red[2] + red[4] + red[6];
        float SS = red[1] + red[3] + red[5] + red[7];
        float mu = S / d;
        float var = SS / d - mu * mu;
        red[8] = mu;
        red[9] = rsqrtf(var + 1e-5f);
    }
    __syncthreads();
    float mu = red[8], inv = red[9];
    float* xw = x + (size_t)r * d;
    if (h0) xw[i0] = (v0 - mu) * inv * g[i0] + b[i0];
    if (h1) xw[i1] = (v1 - mu) * inv * g[i1] + b[i1];
}

// ---------------- build x2: mean over attrs + concat static ----------------
__global__ void build_x2_k(const float* __restrict__ y1, const float* __restrict__ stat,
                           float* __restrict__ x2) {
    int id = blockIdx.x;                 // 192 blocks
    int n = id % N_;
    int b = (id / N_) % B_;
    int s = id / (N_ * B_);
    int orow = b * (S_ * N_) + s * N_ + n;
    for (int c = threadIdx.x; c < D2_; c += 256) {
        float v;
        if (c < C_) {
            int j0 = (s * B_ + b) * A_;
            float acc = 0.f;
            for (int a = 0; a < A_; ++a) acc += y1[(size_t)(n * 64 + j0 + a) * C_ + c];
            v = acc * 0.25f;
        } else {
            v = stat[((size_t)(s * B_ + b) * N_ + n) * AUX_ + (c - C_)];
        }
        x2[(size_t)orow * D2_ + c] = v;
    }
}

// ---------------- build real: mean over nodes ----------------
__global__ void build_real_k(const float* __restrict__ y2, float* __restrict__ real) {
    int id = blockIdx.x;                 // 16 blocks
    int s = id & 1, b = id >> 1;
    for (int c = threadIdx.x; c < D2_; c += 256) {
        float acc = 0.f;
        for (int n = 0; n < N_; ++n) acc += y2[(size_t)(b * 24 + s * N_ + n) * D2_ + c];
        real[(size_t)(b * 2 + s) * D2_ + c] = acc * (1.f / 12.f);
    }
}

// ---------------- regressor: build feats + 2-layer MLP ----------------
__global__ void regressor_k(const float* __restrict__ real, const int* __restrict__ input_idx,
                            const float* __restrict__ kwt, const float* __restrict__ other,
                            const float* __restrict__ w1, const float* __restrict__ b1,
                            const float* __restrict__ w2, const float* __restrict__ b2,
                            float* __restrict__ out) {
    int b = blockIdx.x;                  // 8
    int tid = threadIdx.x;               // 256
    __shared__ float feats[RIN_];
    __shared__ float hh[32];
    for (int i = tid; i < RIN_; i += 256) {
        float v;
        if (i < 64) {
            float acc = 0.f;
            for (int m = 0; m < M_; ++m) acc += kwt[input_idx[b * M_ + m] * EK_ + i];
            v = acc * 0.125f;
        } else if (i < 336) {
            v = real[(size_t)(b * 2 + 0) * D2_ + (i - 64)];
        } else if (i < 400) {
            int e = i - 336;
            float acc = 0.f;
            for (int m = 0; m < M_; ++m) acc += kwt[input_idx[64 + b * M_ + m] * EK_ + e];
            v = acc * 0.125f;
        } else if (i < 672) {
            v = real[(size_t)(b * 2 + 1) * D2_ + (i - 400)];
        } else {
            v = other[b * 64 + (i - 672)];
        }
        feats[i] = v;
    }
    __syncthreads();
    if (tid < 32) {
        float acc = b1[tid];
        const float* wr = w1 + (size_t)tid * RIN_;
        for (int i = 0; i < RIN_; ++i) acc += feats[i] * wr[i];
        hh[tid] = fmaxf(acc, 0.f);
    }
    __syncthreads();
    if (tid == 0) {
        float acc = b2[0];
        for (int j = 0; j < 32; ++j) acc += hh[j] * w2[j];
        out[b] = acc;
    }
}

// ---------------- host ----------------
extern "C" void kernel_launch(void* const* d_in, const int* in_sizes, int n_in,
                              void* d_out, int out_size, void* d_ws, size_t ws_size,
                              hipStream_t stream) {
    const int*   chars      = (const int*)d_in[0];
    const int*   att_type   = (const int*)d_in[1];
    const int*   kw_idx     = (const int*)d_in[2];
    const int*   input_idx  = (const int*)d_in[3];
    const float* stat       = (const float*)d_in[4];
    const float* other      = (const float*)d_in[5];
    const float* char_table = (const float*)d_in[6];
    const float* filter_w   = (const float*)d_in[7];
    const float* filter_b   = (const float*)d_in[8];
    const float* gate_w     = (const float*)d_in[9];
    const float* gate_b     = (const float*)d_in[10];
    const float* mlp_w      = (const float*)d_in[11];
    const float* mlp_b      = (const float*)d_in[12];
    const float* kw_table   = (const float*)d_in[13];
    const float* aline_w    = (const float*)d_in[14];
    const float* aline_b    = (const float*)d_in[15];
    const float* t1_attn_w  = (const float*)d_in[16];
    const float* t1_attn_b  = (const float*)d_in[17];
    const float* t1_ffn_w1  = (const float*)d_in[18];
    const float* t1_ffn_b1  = (const float*)d_in[19];
    const float* t1_ffn_w2  = (const float*)d_in[20];
    const float* t1_ffn_b2  = (const float*)d_in[21];
    const float* t1_ln_g    = (const float*)d_in[22];
    const float* t1_ln_b    = (const float*)d_in[23];
    const float* t2_attn_w  = (const float*)d_in[24];
    const float* t2_attn_b  = (const float*)d_in[25];
    const float* t2_ffn_w1  = (const float*)d_in[26];
    const float* t2_ffn_b1  = (const float*)d_in[27];
    const float* t2_ffn_w2  = (const float*)d_in[28];
    const float* t2_ffn_b2  = (const float*)d_in[29];
    const float* t2_ln_g    = (const float*)d_in[30];
    const float* t2_ln_b    = (const float*)d_in[31];
    const float* reg_w1     = (const float*)d_in[32];
    const float* reg_b1     = (const float*)d_in[33];
    const float* reg_w2     = (const float*)d_in[34];
    const float* reg_b2     = (const float*)d_in[35];

    float* ws   = (float*)d_ws;
    float* tblS = ws;                    // 32768
    float* x1   = tblS + 32768;          // 196608
    float* qkv  = x1 + 196608;           // 589824
    float* obuf = qkv + 589824;          // 196608 (qkv+obuf contiguous: split-K partials)
    float* abuf = obuf + 196608;         // 196608 (unused, kept for layout stability)
    float* hbuf = abuf + 196608;         // 1572864
    float* x2   = hbuf + 1572864;        // 52224
    float* realb= x2 + 52224;            // 4352
    float* pbuf = qkv;                   // split-K partial region (<= 786432 floats)
    // bf16 weights after realb: 5441536 shorts
    unsigned short* wbf = (unsigned short*)(realb + 4352);
    unsigned short* wb_t1_attn = wbf;                 // 524288
    unsigned short* wb_t1_ffn1 = wbf + 524288;        // 1048576
    unsigned short* wb_t1_ffn2 = wbf + 1572864;       // 1048576
    unsigned short* wb_t2_attn = wbf + 2621440;       // 591872
    unsigned short* wb_t2_ffn1 = wbf + 3213312;       // 1114112
    unsigned short* wb_t2_ffn2 = wbf + 4327424;       // 1114112

    auto gemm = [&](const float* A, const unsigned short* Wb, const float* bias, float* Cc,
                    int R, int K, int N, int relu) {
        dim3 g((N + 63) / 64, R / 64, 1);
        gemm_mfma_k<<<g, 256, 0, stream>>>(A, Wb, bias, Cc, R, K, N, relu, K);
    };
    auto gemm_split_ln = [&](const float* A, const unsigned short* Wb, const float* bias,
                             float* x, const float* g, const float* b,
                             int R, int K, int N, int ns) {
        int ksl = ((K + ns - 1) / ns + 31) / 32 * 32;
        dim3 gr((N + 63) / 64, R / 64, ns);
        gemm_mfma_k<<<gr, 256, 0, stream>>>(A, Wb, bias, pbuf, R, K, N, 0, ksl);
        redln_k<<<R, 256, 0, stream>>>(pbuf, bias, x, g, b, N, ns, R * N);
    };

    cvt_w_k<<<2048, 256, 0, stream>>>(t1_attn_w, t1_ffn_w1, t1_ffn_w2,
                                      t2_attn_w, t2_ffn_w1, t2_ffn_w2, wbf);
    scale_table_k<<<128, 256, 0, stream>>>(char_table, tblS);
    attvec_k<<<NSTR_, 512, 0, stream>>>(chars, att_type, kw_idx, tblS,
                                        filter_w, filter_b, gate_w, gate_b,
                                        mlp_w, mlp_b, kw_table, aline_w, aline_b, x1);

    // ---- transformer 1: seq=12, batch=64, d=256 ----
    for (int i = 0; i < 2; ++i) {
        const unsigned short* awb = wb_t1_attn + (size_t)i * 4 * C_ * C_;
        const float* ab = t1_attn_b + (size_t)i * 4 * C_;
        gemm(x1, awb, ab, qkv, 768, C_, 3 * C_, 0);
        attn_k<<<64, 256, 0, stream>>>(qkv, obuf, 12, 64, C_, 0.0625f);
        gemm_split_ln(obuf, awb + 3 * C_ * C_, ab + 3 * C_, x1,
                      t1_ln_g + i * 2 * C_, t1_ln_b + i * 2 * C_, 768, C_, C_, 2);
        gemm(x1, wb_t1_ffn1 + (size_t)i * FF_ * C_, t1_ffn_b1 + i * FF_, hbuf, 768, C_, FF_, 1);
        gemm_split_ln(hbuf, wb_t1_ffn2 + (size_t)i * C_ * FF_, t1_ffn_b2 + i * C_, x1,
                      t1_ln_g + i * 2 * C_ + C_, t1_ln_b + i * 2 * C_ + C_, 768, FF_, C_, 4);
    }

    build_x2_k<<<192, 256, 0, stream>>>(x1, stat, x2);

    // ---- transformer 2: seq=8, batch=24, d=272 ----
    float sc2 = 1.0f / sqrtf(272.0f);
    for (int i = 0; i < 2; ++i) {
        const unsigned short* awb = wb_t2_attn + (size_t)i * 4 * D2_ * D2_;
        const float* ab = t2_attn_b + (size_t)i * 4 * D2_;
        gemm(x2, awb, ab, qkv, 192, D2_, 3 * D2_, 0);
        attn_k<<<24, 256, 0, stream>>>(qkv, obuf, 8, 24, D2_, sc2);
        gemm_split_ln(obuf, awb + 3 * D2_ * D2_, ab + 3 * D2_, x2,
                      t2_ln_g + i * 2 * D2_, t2_ln_b + i * 2 * D2_, 192, D2_, D2_, 4);
        gemm(x2, wb_t2_ffn1 + (size_t)i * FF_ * D2_, t2_ffn_b1 + i * FF_, hbuf, 192, D2_, FF_, 1);
        gemm_split_ln(hbuf, wb_t2_ffn2 + (size_t)i * D2_ * FF_, t2_ffn_b2 + i * D2_, x2,
                      t2_ln_g + i * 2 * D2_ + D2_, t2_ln_b + i * 2 * D2_ + D2_, 192, FF_, D2_, 8);
    }

    build_real_k<<<16, 256, 0, stream>>>(x2, realb);
    regressor_k<<<8, 256, 0, stream>>>(realb, input_idx, kw_table, other,
                                       reg_w1, reg_b1, reg_w2, reg_b2, (float*)d_out);
}

// Round 7
// 327.815 us; speedup vs baseline: 7.3778x; 1.3249x over previous
//
#include <hip/hip_runtime.h>
#include <math.h>

// ---------------- constants ----------------
#define S_ 2
#define B_ 8
#define N_ 12
#define A_ 4
#define L_ 24
#define C_ 256
#define AUX_ 16
#define EK_ 64
#define K_ 256
#define M_ 8
#define OTH_ 32
#define D2_ 272
#define FF_ 2048
#define RIN_ 736
#define NSTR_ (S_*B_*N_*A_)   // 768

typedef __attribute__((ext_vector_type(8))) short short8v;   // bf16x8 MFMA frag
typedef __attribute__((ext_vector_type(4))) float f32x4;     // MFMA acc

__device__ __forceinline__ unsigned short f2bf(float f) {     // RNE f32->bf16
    unsigned u = __float_as_uint(f);
    return (unsigned short)((u + 0x7FFFu + ((u >> 16) & 1u)) >> 16);
}

// ---------------- weight conversion: 6 segments -> contiguous bf16 ----------
__global__ void cvt_w_k(const float* __restrict__ s0, const float* __restrict__ s1,
                        const float* __restrict__ s2, const float* __restrict__ s3,
                        const float* __restrict__ s4, const float* __restrict__ s5,
                        unsigned short* __restrict__ dst) {
    const int T = 5441536 / 4;
    for (int q = blockIdx.x * 256 + threadIdx.x; q < T; q += gridDim.x * 256) {
        int idx = q * 4;
        const float* src; int off;
        if      (idx < 524288)  { src = s0; off = 0; }
        else if (idx < 1572864) { src = s1; off = 524288; }
        else if (idx < 2621440) { src = s2; off = 1572864; }
        else if (idx < 3213312) { src = s3; off = 2621440; }
        else if (idx < 4327424) { src = s4; off = 3213312; }
        else                    { src = s5; off = 4327424; }
        float4 v = *(const float4*)(src + (idx - off));
        ushort4 o;
        o.x = f2bf(v.x); o.y = f2bf(v.y); o.z = f2bf(v.z); o.w = f2bf(v.w);
        *(ushort4*)(dst + idx) = o;
    }
}

// ---------------- K0: renorm char table (max_norm=1) ----------------
__global__ void scale_table_k(const float* __restrict__ tbl, float* __restrict__ out) {
    int r = blockIdx.x;          // 128 rows
    int c = threadIdx.x;         // 256
    float v = tbl[r * C_ + c];
    float sq = v * v;
    for (int off = 32; off; off >>= 1) sq += __shfl_down(sq, off);
    __shared__ float red[4];
    __shared__ float scl;
    if ((c & 63) == 0) red[c >> 6] = sq;
    __syncthreads();
    if (c == 0) {
        float n = sqrtf(red[0] + red[1] + red[2] + red[3]);
        scl = fminf(1.f, 1.f / fmaxf(n, 1e-7f));
    }
    __syncthreads();
    out[r * C_ + c] = v * scl;
}

// ---------------- K1: gated conv / keyword path -> x1 (+ bf16 mirror) ------
// 1024 threads = 4 grp x 256 c. Embeddings staged in LDS (zero-padded rows
// 0 and 25); each grp owns 4 conv channels -> 4 independent exp chains/l.
__global__ void attvec_k(const int* __restrict__ chars, const int* __restrict__ att_type,
                         const int* __restrict__ kw_idx, const float* __restrict__ tblS,
                         const float* __restrict__ fw, const float* __restrict__ fb,
                         const float* __restrict__ gw, const float* __restrict__ gb,
                         const float* __restrict__ mw, const float* __restrict__ mb,
                         const float* __restrict__ kwt, const float* __restrict__ aw,
                         const float* __restrict__ ab, float* __restrict__ x1,
                         unsigned short* __restrict__ x1b) {
    int str = blockIdx.x;        // 0..767
    int tid = threadIdx.x;       // 0..1023
    int grp = tid >> 8;          // 0..3
    int c = tid & 255;
    __shared__ int ch[L_];
    __shared__ float xv[L_ + 2][C_];   // rows 0 and 25 are zero pads
    __shared__ float part[4][C_];
    if (tid < L_) ch[tid] = chars[str * L_ + tid];
    __syncthreads();

    bool kw = (att_type[str] == 1);
    float partial;
    if (kw) {
        const float* kr = kwt + kw_idx[str] * EK_ + grp * 16;
        const float* awr = aw + c * EK_ + grp * 16;
        float acc = (grp == 0) ? ab[c] : 0.f;
        #pragma unroll
        for (int e = 0; e < 16; ++e) acc = fmaf(kr[e], awr[e], acc);
        partial = acc;
    } else {
        // stage embeddings: grp g writes rows g*6+1 .. g*6+6
        #pragma unroll
        for (int i = 0; i < 6; ++i) {
            int l = grp * 6 + i;
            xv[l + 1][c] = tblS[ch[l] * C_ + c];
        }
        if (grp == 0) xv[0][c] = 0.f;
        if (grp == 3) xv[L_ + 1][c] = 0.f;
        __syncthreads();

        // 4 channels per grp, weights hoisted
        float f0[4], f1[4], f2[4], fbv[4], g0[4], g1[4], g2[4], gbv[4], mwv[4];
        #pragma unroll
        for (int oo = 0; oo < 4; ++oo) {
            int o = grp * 4 + oo;
            f0[oo] = 2.f*fw[o*3]; f1[oo] = 2.f*fw[o*3+1]; f2[oo] = 2.f*fw[o*3+2];
            fbv[oo] = 2.f*fb[o];
            g0[oo] = gw[o*3]; g1[oo] = gw[o*3+1]; g2[oo] = gw[o*3+2];
            gbv[oo] = gb[o];
            mwv[oo] = mw[o];
        }
        float osum[4] = {0.f, 0.f, 0.f, 0.f};
        float xm = xv[0][c], x0 = xv[1][c];
        for (int l = 1; l <= L_; ++l) {
            float xp = xv[l + 1][c];
            #pragma unroll
            for (int oo = 0; oo < 4; ++oo) {
                float pf2 = fbv[oo] + f0[oo]*xm + f1[oo]*x0 + f2[oo]*xp;  // = 2*pf
                float pg  = gbv[oo] + g0[oo]*xm + g1[oo]*x0 + g2[oo]*xp;
                pf2 = fminf(fmaxf(pf2, -30.f), 30.f);
                pg  = fminf(fmaxf(pg,  -15.f), 15.f);
                float e1 = __expf(pf2);
                float e2 = __expf(pg);
                float num = (e1 - 1.f) * e2;
                float den = (e1 + 1.f) * (e2 + 1.f);
                osum[oo] = fmaf(num, __builtin_amdgcn_rcpf(den), osum[oo]);
            }
            xm = x0; x0 = xp;
        }
        partial = mwv[0]*osum[0] + mwv[1]*osum[1] + mwv[2]*osum[2] + mwv[3]*osum[3];
    }
    part[grp][c] = partial;
    __syncthreads();
    if (grp == 0) {
        int a = str & 3;
        int n = (str >> 2) % N_;
        int sb = str / (N_ * A_);
        int row = n * 64 + sb * 4 + a;
        float tot = part[0][c] + part[1][c] + part[2][c] + part[3][c];
        float out = kw ? tot : (mb[0] + tot * (1.f / 24.f));
        x1[row * C_ + c] = out;
        x1b[row * C_ + c] = f2bf(out);
    }
}

// ---------------- MFMA GEMM: C[r,n] = Ab[r,:](bf16) . Wb[n,:](bf16) --------
// 64x64 tile / block, 4 waves x (64m x 16n). Zero in-loop conversions.
// obf=1: write bf16 (+bias+relu). gridDim.z>1: f32 partials, no bias.
__global__ void gemm_mfma_k(const unsigned short* __restrict__ Ab,
                            const unsigned short* __restrict__ Wb,
                            const float* __restrict__ bias, float* __restrict__ Cf,
                            unsigned short* __restrict__ Cb,
                            int R, int K, int N, int relu, int kslice, int obf) {
    int tid = threadIdx.x;
    int wave = tid >> 6, lane = tid & 63;
    int fr = lane & 15, fq = lane >> 4;
    int m0 = blockIdx.y * 64;
    int n0 = blockIdx.x * 64 + wave * 16;
    int kbeg = blockIdx.z * kslice;
    int kend = min(kbeg + kslice, K);
    int col = n0 + fr;
    bool bok = col < N;
    const unsigned short* Wrow = Wb + (size_t)col * K;
    const unsigned short* Ar0 = Ab + (size_t)(m0 + fr) * K;
    const unsigned short* Ar1 = Ab + (size_t)(m0 + 16 + fr) * K;
    const unsigned short* Ar2 = Ab + (size_t)(m0 + 32 + fr) * K;
    const unsigned short* Ar3 = Ab + (size_t)(m0 + 48 + fr) * K;

    f32x4 acc0 = {0.f,0.f,0.f,0.f}, acc1 = {0.f,0.f,0.f,0.f};
    f32x4 acc2 = {0.f,0.f,0.f,0.f}, acc3 = {0.f,0.f,0.f,0.f};
    const short8v z8 = {0,0,0,0,0,0,0,0};

    for (int kt = kbeg; kt < kend; kt += 32) {
        int kl = kt + fq * 8;
        bool kv = (kl + 8 <= kend);
        short8v bf  = (bok && kv) ? *(const short8v*)(Wrow + kl) : z8;
        short8v af0 = kv ? *(const short8v*)(Ar0 + kl) : z8;
        short8v af1 = kv ? *(const short8v*)(Ar1 + kl) : z8;
        short8v af2 = kv ? *(const short8v*)(Ar2 + kl) : z8;
        short8v af3 = kv ? *(const short8v*)(Ar3 + kl) : z8;
        acc0 = __builtin_amdgcn_mfma_f32_16x16x32_bf16(af0, bf, acc0, 0, 0, 0);
        acc1 = __builtin_amdgcn_mfma_f32_16x16x32_bf16(af1, bf, acc1, 0, 0, 0);
        acc2 = __builtin_amdgcn_mfma_f32_16x16x32_bf16(af2, bf, acc2, 0, 0, 0);
        acc3 = __builtin_amdgcn_mfma_f32_16x16x32_bf16(af3, bf, acc3, 0, 0, 0);
    }

    if (!bok) return;
    bool direct = (gridDim.z == 1);
    float bv = direct ? bias[col] : 0.f;
    float* outf = direct ? Cf : (Cf + (size_t)blockIdx.z * R * N);
#define STOREACC(accv, mi) do {                                           \
        _Pragma("unroll")                                                 \
        for (int j = 0; j < 4; ++j) {                                     \
            int row = m0 + (mi)*16 + fq * 4 + j;                          \
            float v = accv[j] + bv;                                       \
            if (direct && relu) v = fmaxf(v, 0.f);                        \
            if (obf) Cb[(size_t)row * N + col] = f2bf(v);                 \
            else     outf[(size_t)row * N + col] = v;                     \
        }                                                                 \
    } while (0)
    STOREACC(acc0, 0); STOREACC(acc1, 1); STOREACC(acc2, 2); STOREACC(acc3, 3);
#undef STOREACC
}

// ---------------- attention: f32 in (qkv), bf16 out ------------------------
__global__ void attn_k(const float* __restrict__ qkv, unsigned short* __restrict__ ob,
                       int seq, int batch, int d, float scale) {
    __shared__ float sm[3 * 12 * 256];
    __shared__ float sc[12 * 12];
    int j = blockIdx.x, tid = threadIdx.x;
    int sd = seq * d, s3 = 3 * d;
    float* qs = sm;
    float* ks = sm + sd;
    float* vs = sm + 2 * sd;
    for (int idx = tid; idx < sd; idx += 256) {
        int s = idx / d, c = idx - s * d;
        const float* base = qkv + (size_t)(s * batch + j) * s3 + c;
        qs[idx] = base[0];
        ks[idx] = base[d];
        vs[idx] = base[2 * d];
    }
    __syncthreads();
    for (int p = tid; p < seq * seq; p += 256) {
        int s = p / seq, t = p - s * seq;
        float acc = 0.f;
        const float* qp = qs + s * d;
        const float* kp = ks + t * d;
        for (int c = 0; c < d; ++c) acc += qp[c] * kp[c];
        sc[p] = acc * scale;
    }
    __syncthreads();
    if (tid < seq) {
        float m = -1e30f;
        for (int t = 0; t < seq; ++t) m = fmaxf(m, sc[tid * seq + t]);
        float ssum = 0.f;
        for (int t = 0; t < seq; ++t) {
            float e = __expf(sc[tid * seq + t] - m);
            sc[tid * seq + t] = e;
            ssum += e;
        }
        float inv = 1.f / ssum;
        for (int t = 0; t < seq; ++t) sc[tid * seq + t] *= inv;
    }
    __syncthreads();
    for (int c = tid; c < d; c += 256) {
        for (int s = 0; s < seq; ++s) {
            float acc = 0.f;
            for (int t = 0; t < seq; ++t) acc += sc[s * seq + t] * vs[t * d + c];
            ob[(size_t)(s * batch + j) * d + c] = f2bf(acc);
        }
    }
}

// ------- fused split-K reduce + bias + residual + LayerNorm (f32 + bf16) ---
__global__ void redln_k(const float* __restrict__ part, const float* __restrict__ bias,
                        float* __restrict__ x, unsigned short* __restrict__ xb,
                        const float* __restrict__ g, const float* __restrict__ b,
                        int d, int NS, int RN) {
    int r = blockIdx.x, tid = threadIdx.x;
    __shared__ float red[10];
    const float* xr = x + (size_t)r * d;
    int i0 = tid, i1 = tid + 256;
    bool h0 = i0 < d, h1 = i1 < d;
    float v0 = 0.f, v1 = 0.f;
    if (h0) {
        v0 = xr[i0] + bias[i0];
        for (int z = 0; z < NS; ++z) v0 += part[(size_t)z * RN + (size_t)r * d + i0];
    }
    if (h1) {
        v1 = xr[i1] + bias[i1];
        for (int z = 0; z < NS; ++z) v1 += part[(size_t)z * RN + (size_t)r * d + i1];
    }
    float s = v0 + v1, ss = v0 * v0 + v1 * v1;
    for (int off = 32; off; off >>= 1) {
        s += __shfl_down(s, off);
        ss += __shfl_down(ss, off);
    }
    if ((tid & 63) == 0) { red[(tid >> 6) * 2] = s; red[(tid >> 6) * 2 + 1] = ss; }
    __syncthreads();
    if (tid == 0) {
        float S = red[0] + red[2] + red[4] + red[6];
        float SS = red[1] + red[3] + red[5] + red[7];
        float mu = S / d;
        float var = SS / d - mu * mu;
        red[8] = mu;
        red[9] = rsqrtf(var + 1e-5f);
    }
    __syncthreads();
    float mu = red[8], inv = red[9];
    float* xw = x + (size_t)r * d;
    if (h0) {
        float o = (v0 - mu) * inv * g[i0] + b[i0];
        xw[i0] = o; xb[(size_t)r * d + i0] = f2bf(o);
    }
    if (h1) {
        float o = (v1 - mu) * inv * g[i1] + b[i1];
        xw[i1] = o; xb[(size_t)r * d + i1] = f2bf(o);
    }
}

// ---------------- build x2: mean over attrs + concat static ----------------
__global__ void build_x2_k(const float* __restrict__ y1, const float* __restrict__ stat,
                           float* __restrict__ x2, unsigned short* __restrict__ x2b) {
    int id = blockIdx.x;                 // 192 blocks
    int n = id % N_;
    int b = (id / N_) % B_;
    int s = id / (N_ * B_);
    int orow = b * (S_ * N_) + s * N_ + n;
    for (int c = threadIdx.x; c < D2_; c += 256) {
        float v;
        if (c < C_) {
            int j0 = (s * B_ + b) * A_;
            float acc = 0.f;
            for (int a = 0; a < A_; ++a) acc += y1[(size_t)(n * 64 + j0 + a) * C_ + c];
            v = acc * 0.25f;
        } else {
            v = stat[((size_t)(s * B_ + b) * N_ + n) * AUX_ + (c - C_)];
        }
        x2[(size_t)orow * D2_ + c] = v;
        x2b[(size_t)orow * D2_ + c] = f2bf(v);
    }
}

// ---------------- build real: mean over nodes ----------------
__global__ void build_real_k(const float* __restrict__ y2, float* __restrict__ real) {
    int id = blockIdx.x;                 // 16 blocks
    int s = id & 1, b = id >> 1;
    for (int c = threadIdx.x; c < D2_; c += 256) {
        float acc = 0.f;
        for (int n = 0; n < N_; ++n) acc += y2[(size_t)(b * 24 + s * N_ + n) * D2_ + c];
        real[(size_t)(b * 2 + s) * D2_ + c] = acc * (1.f / 12.f);
    }
}

// ---------------- regressor: build feats + 2-layer MLP ----------------
__global__ void regressor_k(const float* __restrict__ real, const int* __restrict__ input_idx,
                            const float* __restrict__ kwt, const float* __restrict__ other,
                            const float* __restrict__ w1, const float* __restrict__ b1,
                            const float* __restrict__ w2, const float* __restrict__ b2,
                            float* __restrict__ out) {
    int b = blockIdx.x;                  // 8
    int tid = threadIdx.x;               // 256
    __shared__ float feats[RIN_];
    __shared__ float hh[32];
    for (int i = tid; i < RIN_; i += 256) {
        float v;
        if (i < 64) {
            float acc = 0.f;
            for (int m = 0; m < M_; ++m) acc += kwt[input_idx[b * M_ + m] * EK_ + i];
            v = acc * 0.125f;
        } else if (i < 336) {
            v = real[(size_t)(b * 2 + 0) * D2_ + (i - 64)];
        } else if (i < 400) {
            int e = i - 336;
            float acc = 0.f;
            for (int m = 0; m < M_; ++m) acc += kwt[input_idx[64 + b * M_ + m] * EK_ + e];
            v = acc * 0.125f;
        } else if (i < 672) {
            v = real[(size_t)(b * 2 + 1) * D2_ + (i - 400)];
        } else {
            v = other[b * 64 + (i - 672)];
        }
        feats[i] = v;
    }
    __syncthreads();
    if (tid < 32) {
        float acc = b1[tid];
        const float* wr = w1 + (size_t)tid * RIN_;
        for (int i = 0; i < RIN_; ++i) acc += feats[i] * wr[i];
        hh[tid] = fmaxf(acc, 0.f);
    }
    __syncthreads();
    if (tid == 0) {
        float acc = b2[0];
        for (int j = 0; j < 32; ++j) acc += hh[j] * w2[j];
        out[b] = acc;
    }
}

// ---------------- host ----------------
extern "C" void kernel_launch(void* const* d_in, const int* in_sizes, int n_in,
                              void* d_out, int out_size, void* d_ws, size_t ws_size,
                              hipStream_t stream) {
    const int*   chars      = (const int*)d_in[0];
    const int*   att_type   = (const int*)d_in[1];
    const int*   kw_idx     = (const int*)d_in[2];
    const int*   input_idx  = (const int*)d_in[3];
    const float* stat       = (const float*)d_in[4];
    const float* other      = (const float*)d_in[5];
    const float* char_table = (const float*)d_in[6];
    const float* filter_w   = (const float*)d_in[7];
    const float* filter_b   = (const float*)d_in[8];
    const float* gate_w     = (const float*)d_in[9];
    const float* gate_b     = (const float*)d_in[10];
    const float* mlp_w      = (const float*)d_in[11];
    const float* mlp_b      = (const float*)d_in[12];
    const float* kw_table   = (const float*)d_in[13];
    const float* aline_w    = (const float*)d_in[14];
    const float* aline_b    = (const float*)d_in[15];
    const float* t1_attn_w  = (const float*)d_in[16];
    const float* t1_attn_b  = (const float*)d_in[17];
    const float* t1_ffn_w1  = (const float*)d_in[18];
    const float* t1_ffn_b1  = (const float*)d_in[19];
    const float* t1_ffn_w2  = (const float*)d_in[20];
    const float* t1_ffn_b2  = (const float*)d_in[21];
    const float* t1_ln_g    = (const float*)d_in[22];
    const float* t1_ln_b    = (const float*)d_in[23];
    const float* t2_attn_w  = (const float*)d_in[24];
    const float* t2_attn_b  = (const float*)d_in[25];
    const float* t2_ffn_w1  = (const float*)d_in[26];
    const float* t2_ffn_b1  = (const float*)d_in[27];
    const float* t2_ffn_w2  = (const float*)d_in[28];
    const float* t2_ffn_b2  = (const float*)d_in[29];
    const float* t2_ln_g    = (const float*)d_in[30];
    const float* t2_ln_b    = (const float*)d_in[31];
    const float* reg_w1     = (const float*)d_in[32];
    const float* reg_b1     = (const float*)d_in[33];
    const float* reg_w2     = (const float*)d_in[34];
    const float* reg_b2     = (const float*)d_in[35];

    float* ws   = (float*)d_ws;
    float* tblS = ws;                          // 32768
    float* x1   = tblS + 32768;                // 196608
    float* qkv  = x1 + 196608;                 // 589824 (f32)
    float* pbuf = qkv + 589824;                // 786432 (split-K partials)
    float* x2   = pbuf + 786432;               // 52224
    float* realb= x2 + 52224;                  // 4352
    unsigned short* x1b = (unsigned short*)(realb + 4352);   // 196608 shorts
    unsigned short* obb = x1b + 196608;        // 196608 shorts
    unsigned short* hb  = obb + 196608;        // 1572864 shorts
    unsigned short* x2b = hb + 1572864;        // 52224 shorts
    unsigned short* wbf = x2b + 52224 + 16;    // 5441536 shorts (16B aligned pad)
    unsigned short* wb_t1_attn = wbf;
    unsigned short* wb_t1_ffn1 = wbf + 524288;
    unsigned short* wb_t1_ffn2 = wbf + 1572864;
    unsigned short* wb_t2_attn = wbf + 2621440;
    unsigned short* wb_t2_ffn1 = wbf + 3213312;
    unsigned short* wb_t2_ffn2 = wbf + 4327424;

    // direct f32 out (QKV)
    auto gemm_f32 = [&](const unsigned short* A, const unsigned short* Wb, const float* bias,
                        float* Cc, int R, int Kk, int N) {
        dim3 g((N + 63) / 64, R / 64, 1);
        gemm_mfma_k<<<g, 256, 0, stream>>>(A, Wb, bias, Cc, (unsigned short*)0,
                                           R, Kk, N, 0, Kk, 0);
    };
    // direct bf16 out + relu (ffn1)
    auto gemm_bf16 = [&](const unsigned short* A, const unsigned short* Wb, const float* bias,
                         unsigned short* Cc, int R, int Kk, int N) {
        dim3 g((N + 63) / 64, R / 64, 1);
        gemm_mfma_k<<<g, 256, 0, stream>>>(A, Wb, bias, (float*)0, Cc,
                                           R, Kk, N, 1, Kk, 1);
    };
    // split-K + fused reduce+bias+residual+LN (f32 + bf16 mirror)
    auto gemm_split_ln = [&](const unsigned short* A, const unsigned short* Wb,
                             const float* bias, float* x, unsigned short* xb,
                             const float* g, const float* b,
                             int R, int Kk, int N, int ns) {
        int ksl = ((Kk + ns - 1) / ns + 31) / 32 * 32;
        dim3 gr((N + 63) / 64, R / 64, ns);
        gemm_mfma_k<<<gr, 256, 0, stream>>>(A, Wb, bias, pbuf, (unsigned short*)0,
                                            R, Kk, N, 0, ksl, 0);
        redln_k<<<R, 256, 0, stream>>>(pbuf, bias, x, xb, g, b, N, ns, R * N);
    };

    cvt_w_k<<<2048, 256, 0, stream>>>(t1_attn_w, t1_ffn_w1, t1_ffn_w2,
                                      t2_attn_w, t2_ffn_w1, t2_ffn_w2, wbf);
    scale_table_k<<<128, 256, 0, stream>>>(char_table, tblS);
    attvec_k<<<NSTR_, 1024, 0, stream>>>(chars, att_type, kw_idx, tblS,
                                         filter_w, filter_b, gate_w, gate_b,
                                         mlp_w, mlp_b, kw_table, aline_w, aline_b,
                                         x1, x1b);

    // ---- transformer 1: seq=12, batch=64, d=256 ----
    for (int i = 0; i < 2; ++i) {
        const unsigned short* awb = wb_t1_attn + (size_t)i * 4 * C_ * C_;
        const float* ab = t1_attn_b + (size_t)i * 4 * C_;
        gemm_f32(x1b, awb, ab, qkv, 768, C_, 3 * C_);
        attn_k<<<64, 256, 0, stream>>>(qkv, obb, 12, 64, C_, 0.0625f);
        gemm_split_ln(obb, awb + 3 * C_ * C_, ab + 3 * C_, x1, x1b,
                      t1_ln_g + i * 2 * C_, t1_ln_b + i * 2 * C_, 768, C_, C_, 2);
        gemm_bf16(x1b, wb_t1_ffn1 + (size_t)i * FF_ * C_, t1_ffn_b1 + i * FF_, hb, 768, C_, FF_);
        gemm_split_ln(hb, wb_t1_ffn2 + (size_t)i * C_ * FF_, t1_ffn_b2 + i * C_, x1, x1b,
                      t1_ln_g + i * 2 * C_ + C_, t1_ln_b + i * 2 * C_ + C_, 768, FF_, C_, 4);
    }

    build_x2_k<<<192, 256, 0, stream>>>(x1, stat, x2, x2b);

    // ---- transformer 2: seq=8, batch=24, d=272 ----
    float sc2 = 1.0f / sqrtf(272.0f);
    for (int i = 0; i < 2; ++i) {
        const unsigned short* awb = wb_t2_attn + (size_t)i * 4 * D2_ * D2_;
        const float* ab = t2_attn_b + (size_t)i * 4 * D2_;
        gemm_f32(x2b, awb, ab, qkv, 192, D2_, 3 * D2_);
        attn_k<<<24, 256, 0, stream>>>(qkv, obb, 8, 24, D2_, sc2);
        gemm_split_ln(obb, awb + 3 * D2_ * D2_, ab + 3 * D2_, x2, x2b,
                      t2_ln_g + i * 2 * D2_, t2_ln_b + i * 2 * D2_, 192, D2_, D2_, 4);
        gemm_bf16(x2b, wb_t2_ffn1 + (size_t)i * FF_ * D2_, t2_ffn_b1 + i * FF_, hb, 192, D2_, FF_);
        gemm_split_ln(hb, wb_t2_ffn2 + (size_t)i * D2_ * FF_, t2_ffn_b2 + i * D2_, x2, x2b,
                      t2_ln_g + i * 2 * D2_ + D2_, t2_ln_b + i * 2 * D2_ + D2_, 192, FF_, D2_, 8);
    }

    build_real_k<<<16, 256, 0, stream>>>(x2, realb);
    regressor_k<<<8, 256, 0, stream>>>(realb, input_idx, kw_table, other,
                                       reg_w1, reg_b1, reg_w2, reg_b2, (float*)d_out);
}

// Round 8
// 326.457 us; speedup vs baseline: 7.4085x; 1.0042x over previous
//
#include <hip/hip_runtime.h>
#include <math.h>

// ---------------- constants ----------------
#define S_ 2
#define B_ 8
#define N_ 12
#define A_ 4
#define L_ 24
#define C_ 256
#define AUX_ 16
#define EK_ 64
#define K_ 256
#define M_ 8
#define OTH_ 32
#define D2_ 272
#define FF_ 2048
#define RIN_ 736
#define NSTR_ (S_*B_*N_*A_)   // 768

typedef __attribute__((ext_vector_type(8))) short short8v;   // bf16x8 MFMA frag
typedef __attribute__((ext_vector_type(4))) float f32x4;     // MFMA acc

__device__ __forceinline__ unsigned short f2bf(float f) {     // RNE f32->bf16
    unsigned u = __float_as_uint(f);
    return (unsigned short)((u + 0x7FFFu + ((u >> 16) & 1u)) >> 16);
}

// ---------------- weight conversion: 6 segments -> contiguous bf16 ----------
__global__ void cvt_w_k(const float* __restrict__ s0, const float* __restrict__ s1,
                        const float* __restrict__ s2, const float* __restrict__ s3,
                        const float* __restrict__ s4, const float* __restrict__ s5,
                        unsigned short* __restrict__ dst) {
    const int T = 5441536 / 4;
    for (int q = blockIdx.x * 256 + threadIdx.x; q < T; q += gridDim.x * 256) {
        int idx = q * 4;
        const float* src; int off;
        if      (idx < 524288)  { src = s0; off = 0; }
        else if (idx < 1572864) { src = s1; off = 524288; }
        else if (idx < 2621440) { src = s2; off = 1572864; }
        else if (idx < 3213312) { src = s3; off = 2621440; }
        else if (idx < 4327424) { src = s4; off = 3213312; }
        else                    { src = s5; off = 4327424; }
        float4 v = *(const float4*)(src + (idx - off));
        ushort4 o;
        o.x = f2bf(v.x); o.y = f2bf(v.y); o.z = f2bf(v.z); o.w = f2bf(v.w);
        *(ushort4*)(dst + idx) = o;
    }
}

// ---------------- K0: renorm char table (max_norm=1) ----------------
__global__ void scale_table_k(const float* __restrict__ tbl, float* __restrict__ out) {
    int r = blockIdx.x;          // 128 rows
    int c = threadIdx.x;         // 256
    float v = tbl[r * C_ + c];
    float sq = v * v;
    for (int off = 32; off; off >>= 1) sq += __shfl_down(sq, off);
    __shared__ float red[4];
    __shared__ float scl;
    if ((c & 63) == 0) red[c >> 6] = sq;
    __syncthreads();
    if (c == 0) {
        float n = sqrtf(red[0] + red[1] + red[2] + red[3]);
        scl = fminf(1.f, 1.f / fmaxf(n, 1e-7f));
    }
    __syncthreads();
    out[r * C_ + c] = v * scl;
}

// ---------------- K1: gated conv / keyword via atomic work queue -----------
// 512 persistent blocks (2/CU) x 1024 thr (4 grp x 256 c). Blocks pop string
// indices from ctr (memset to 0 each launch) -> near-perfect load balance
// despite random kw/conv mix. Output independent of pop order.
__global__ void attvec_k(const int* __restrict__ chars, const int* __restrict__ att_type,
                         const int* __restrict__ kw_idx, const float* __restrict__ tblS,
                         const float* __restrict__ fw, const float* __restrict__ fb,
                         const float* __restrict__ gw, const float* __restrict__ gb,
                         const float* __restrict__ mw, const float* __restrict__ mb,
                         const float* __restrict__ kwt, const float* __restrict__ aw,
                         const float* __restrict__ ab, float* __restrict__ x1,
                         unsigned short* __restrict__ x1b, int* __restrict__ ctr) {
    int tid = threadIdx.x;       // 0..1023
    int grp = tid >> 8;          // 0..3
    int c = tid & 255;
    __shared__ int su;
    __shared__ int ch[L_];
    __shared__ float xv[L_ + 2][C_];   // rows 0 and 25 are zero pads
    __shared__ float part[4][C_];

    const float L2E = 1.44269504f;     // exp2 prescale (native v_exp_f32 is 2^x)
    float f0[4], f1[4], f2[4], fbv[4], g0[4], g1[4], g2[4], gbv[4], mwv[4];
    #pragma unroll
    for (int oo = 0; oo < 4; ++oo) {
        int o = grp * 4 + oo;
        f0[oo] = 2.f*L2E*fw[o*3]; f1[oo] = 2.f*L2E*fw[o*3+1]; f2[oo] = 2.f*L2E*fw[o*3+2];
        fbv[oo] = 2.f*L2E*fb[o];
        g0[oo] = L2E*gw[o*3]; g1[oo] = L2E*gw[o*3+1]; g2[oo] = L2E*gw[o*3+2];
        gbv[oo] = L2E*gb[o];
        mwv[oo] = mw[o];
    }

    for (;;) {
        if (tid == 0) su = atomicAdd(ctr, 1);
        __syncthreads();
        int str = su;
        if (str >= NSTR_) break;                 // uniform exit
        bool kw = (att_type[str] == 1);
        float partial;
        if (kw) {
            const float* kr = kwt + kw_idx[str] * EK_ + grp * 16;
            const float* awr = aw + c * EK_ + grp * 16;
            float acc = (grp == 0) ? ab[c] : 0.f;
            #pragma unroll
            for (int e = 0; e < 16; ++e) acc = fmaf(kr[e], awr[e], acc);
            partial = acc;
        } else {
            if (tid < L_) ch[tid] = chars[str * L_ + tid];
            __syncthreads();
            #pragma unroll
            for (int i = 0; i < 6; ++i) {        // grp g stages rows g*6+1..+6
                int l = grp * 6 + i;
                xv[l + 1][c] = tblS[ch[l] * C_ + c];
            }
            if (grp == 0) xv[0][c] = 0.f;
            if (grp == 3) xv[L_ + 1][c] = 0.f;
            __syncthreads();

            float osum[4] = {0.f, 0.f, 0.f, 0.f};
            float xm = xv[0][c], x0 = xv[1][c];
            for (int l = 1; l <= L_; ++l) {
                float xp = xv[l + 1][c];
                #pragma unroll
                for (int oo = 0; oo < 4; ++oo) {
                    float pf2 = fbv[oo] + f0[oo]*xm + f1[oo]*x0 + f2[oo]*xp; // 2*log2e*pf
                    float pg  = gbv[oo] + g0[oo]*xm + g1[oo]*x0 + g2[oo]*xp; // log2e*pg
                    pf2 = fminf(fmaxf(pf2, -43.f), 43.f);
                    pg  = fminf(fmaxf(pg,  -22.f), 22.f);
                    float e1 = __builtin_amdgcn_exp2f(pf2);
                    float e2 = __builtin_amdgcn_exp2f(pg);
                    float num = (e1 - 1.f) * e2;
                    float den = (e1 + 1.f) * (e2 + 1.f);
                    osum[oo] = fmaf(num, __builtin_amdgcn_rcpf(den), osum[oo]);
                }
                xm = x0; x0 = xp;
            }
            partial = mwv[0]*osum[0] + mwv[1]*osum[1] + mwv[2]*osum[2] + mwv[3]*osum[3];
            __syncthreads();                      // xv reads done before next overwrite
        }
        part[grp][c] = partial;
        __syncthreads();
        if (grp == 0) {
            int a = str & 3;
            int n = (str >> 2) % N_;
            int sb = str / (N_ * A_);
            int row = n * 64 + sb * 4 + a;
            float tot = part[0][c] + part[1][c] + part[2][c] + part[3][c];
            float out = kw ? tot : (mb[0] + tot * (1.f / 24.f));
            x1[row * C_ + c] = out;
            x1b[row * C_ + c] = f2bf(out);
        }
        __syncthreads();                          // part reads done before next iter
    }
}

// ---------------- MFMA GEMM with register prefetch ------------------------
// 64x64 tile / block, 4 waves x (64m x 16n). Loads for K-step t+1 issued
// before the MFMAs of step t (1-deep reg pipeline; no launch_bounds).
__global__ void gemm_mfma_k(const unsigned short* __restrict__ Ab,
                            const unsigned short* __restrict__ Wb,
                            const float* __restrict__ bias, float* __restrict__ Cf,
                            unsigned short* __restrict__ Cb,
                            int R, int K, int N, int relu, int kslice, int obf) {
    int tid = threadIdx.x;
    int wave = tid >> 6, lane = tid & 63;
    int fr = lane & 15, fq = lane >> 4;
    int m0 = blockIdx.y * 64;
    int n0 = blockIdx.x * 64 + wave * 16;
    int kbeg = blockIdx.z * kslice;
    int kend = min(kbeg + kslice, K);
    int col = n0 + fr;
    bool bok = col < N;
    const unsigned short* Wrow = Wb + (size_t)col * K;
    const unsigned short* Ar0 = Ab + (size_t)(m0 + fr) * K;
    const unsigned short* Ar1 = Ab + (size_t)(m0 + 16 + fr) * K;
    const unsigned short* Ar2 = Ab + (size_t)(m0 + 32 + fr) * K;
    const unsigned short* Ar3 = Ab + (size_t)(m0 + 48 + fr) * K;

    f32x4 acc0 = {0.f,0.f,0.f,0.f}, acc1 = {0.f,0.f,0.f,0.f};
    f32x4 acc2 = {0.f,0.f,0.f,0.f}, acc3 = {0.f,0.f,0.f,0.f};
    const short8v z8 = {0,0,0,0,0,0,0,0};
    short8v pb, pa0, pa1, pa2, pa3;

#define LDSET(ktv) do {                                                   \
        int kl2 = (ktv) + fq * 8;                                         \
        bool kv2 = (kl2 + 8 <= kend);                                     \
        pb  = (bok && kv2) ? *(const short8v*)(Wrow + kl2) : z8;          \
        pa0 = kv2 ? *(const short8v*)(Ar0 + kl2) : z8;                    \
        pa1 = kv2 ? *(const short8v*)(Ar1 + kl2) : z8;                    \
        pa2 = kv2 ? *(const short8v*)(Ar2 + kl2) : z8;                    \
        pa3 = kv2 ? *(const short8v*)(Ar3 + kl2) : z8;                    \
    } while (0)

    LDSET(kbeg);
    for (int kt = kbeg; kt < kend; kt += 32) {
        short8v bf = pb, af0 = pa0, af1 = pa1, af2 = pa2, af3 = pa3;
        if (kt + 32 < kend) LDSET(kt + 32);       // in flight during MFMAs
        acc0 = __builtin_amdgcn_mfma_f32_16x16x32_bf16(af0, bf, acc0, 0, 0, 0);
        acc1 = __builtin_amdgcn_mfma_f32_16x16x32_bf16(af1, bf, acc1, 0, 0, 0);
        acc2 = __builtin_amdgcn_mfma_f32_16x16x32_bf16(af2, bf, acc2, 0, 0, 0);
        acc3 = __builtin_amdgcn_mfma_f32_16x16x32_bf16(af3, bf, acc3, 0, 0, 0);
    }
#undef LDSET

    if (!bok) return;
    bool direct = (gridDim.z == 1);
    float bv = direct ? bias[col] : 0.f;
    float* outf = direct ? Cf : (Cf + (size_t)blockIdx.z * R * N);
#define STOREACC(accv, mi) do {                                           \
        _Pragma("unroll")                                                 \
        for (int j = 0; j < 4; ++j) {                                     \
            int row = m0 + (mi)*16 + fq * 4 + j;                          \
            float v = accv[j] + bv;                                       \
            if (direct && relu) v = fmaxf(v, 0.f);                        \
            if (obf) Cb[(size_t)row * N + col] = f2bf(v);                 \
            else     outf[(size_t)row * N + col] = v;                     \
        }                                                                 \
    } while (0)
    STOREACC(acc0, 0); STOREACC(acc1, 1); STOREACC(acc2, 2); STOREACC(acc3, 3);
#undef STOREACC
}

// ---------------- attention: 4-lane score dot, padded LDS ------------------
__global__ void attn_k(const float* __restrict__ qkv, unsigned short* __restrict__ ob,
                       int seq, int batch, int d, float scale) {
    __shared__ float sm[3 * 12 * 260];     // row stride d+4 kills bank conflicts
    __shared__ float sc[12 * 12];
    int j = blockIdx.x, tid = threadIdx.x;
    int dp = d + 4;
    int s3 = 3 * d;
    float* qs = sm;
    float* ks = sm + 12 * 260;
    float* vs = sm + 2 * 12 * 260;
    for (int idx = tid; idx < seq * d; idx += 256) {
        int s = idx / d, cc = idx - s * d;
        const float* base = qkv + (size_t)(s * batch + j) * s3 + cc;
        qs[s * dp + cc] = base[0];
        ks[s * dp + cc] = base[d];
        vs[s * dp + cc] = base[2 * d];
    }
    __syncthreads();
    for (int p4 = tid; p4 < seq * seq * 4; p4 += 256) {
        int p = p4 >> 2, sub = p4 & 3;
        int s = p / seq, t = p - s * seq;
        const float* qp = qs + s * dp;
        const float* kp = ks + t * dp;
        float acc = 0.f;
        for (int cc = sub; cc < d; cc += 4) acc = fmaf(qp[cc], kp[cc], acc);
        acc += __shfl_xor(acc, 1);
        acc += __shfl_xor(acc, 2);
        if (sub == 0) sc[p] = acc * scale;
    }
    __syncthreads();
    if (tid < seq) {
        float m = -1e30f;
        for (int t = 0; t < seq; ++t) m = fmaxf(m, sc[tid * seq + t]);
        float ssum = 0.f;
        for (int t = 0; t < seq; ++t) {
            float e = __expf(sc[tid * seq + t] - m);
            sc[tid * seq + t] = e;
            ssum += e;
        }
        float inv = 1.f / ssum;
        for (int t = 0; t < seq; ++t) sc[tid * seq + t] *= inv;
    }
    __syncthreads();
    for (int c = tid; c < d; c += 256) {
        for (int s = 0; s < seq; ++s) {
            float acc = 0.f;
            for (int t = 0; t < seq; ++t) acc = fmaf(sc[s * seq + t], vs[t * dp + c], acc);
            ob[(size_t)(s * batch + j) * d + c] = f2bf(acc);
        }
    }
}

// ------- fused split-K reduce + bias + residual + LayerNorm (f32 + bf16) ---
__global__ void redln_k(const float* __restrict__ part, const float* __restrict__ bias,
                        float* __restrict__ x, unsigned short* __restrict__ xb,
                        const float* __restrict__ g, const float* __restrict__ b,
                        int d, int NS, int RN) {
    int r = blockIdx.x, tid = threadIdx.x;
    __shared__ float red[10];
    const float* xr = x + (size_t)r * d;
    int i0 = tid, i1 = tid + 256;
    bool h0 = i0 < d, h1 = i1 < d;
    float v0 = 0.f, v1 = 0.f;
    if (h0) {
        v0 = xr[i0] + bias[i0];
        for (int z = 0; z < NS; ++z) v0 += part[(size_t)z * RN + (size_t)r * d + i0];
    }
    if (h1) {
        v1 = xr[i1] + bias[i1];
        for (int z = 0; z < NS; ++z) v1 += part[(size_t)z * RN + (size_t)r * d + i1];
    }
    float s = v0 + v1, ss = v0 * v0 + v1 * v1;
    for (int off = 32; off; off >>= 1) {
        s += __shfl_down(s, off);
        ss += __shfl_down(ss, off);
    }
    if ((tid & 63) == 0) { red[(tid >> 6) * 2] = s; red[(tid >> 6) * 2 + 1] = ss; }
    __syncthreads();
    if (tid == 0) {
        float S = red[0] + red[2] + red[4] + red[6];
        float SS = red[1] + red[3] + red[5] + red[7];
        float mu = S / d;
        float var = SS / d - mu * mu;
        red[8] = mu;
        red[9] = rsqrtf(var + 1e-5f);
    }
    __syncthreads();
    float mu = red[8], inv = red[9];
    float* xw = x + (size_t)r * d;
    if (h0) {
        float o = (v0 - mu) * inv * g[i0] + b[i0];
        xw[i0] = o; xb[(size_t)r * d + i0] = f2bf(o);
    }
    if (h1) {
        float o = (v1 - mu) * inv * g[i1] + b[i1];
        xw[i1] = o; xb[(size_t)r * d + i1] = f2bf(o);
    }
}

// ---------------- build x2: mean over attrs + concat static ----------------
__global__ void build_x2_k(const float* __restrict__ y1, const float* __restrict__ stat,
                           float* __restrict__ x2, unsigned short* __restrict__ x2b) {
    int id = blockIdx.x;                 // 192 blocks
    int n = id % N_;
    int b = (id / N_) % B_;
    int s = id / (N_ * B_);
    int orow = b * (S_ * N_) + s * N_ + n;
    for (int c = threadIdx.x; c < D2_; c += 256) {
        float v;
        if (c < C_) {
            int j0 = (s * B_ + b) * A_;
            float acc = 0.f;
            for (int a = 0; a < A_; ++a) acc += y1[(size_t)(n * 64 + j0 + a) * C_ + c];
            v = acc * 0.25f;
        } else {
            v = stat[((size_t)(s * B_ + b) * N_ + n) * AUX_ + (c - C_)];
        }
        x2[(size_t)orow * D2_ + c] = v;
        x2b[(size_t)orow * D2_ + c] = f2bf(v);
    }
}

// ---------------- build real: mean over nodes ----------------
__global__ void build_real_k(const float* __restrict__ y2, float* __restrict__ real) {
    int id = blockIdx.x;                 // 16 blocks
    int s = id & 1, b = id >> 1;
    for (int c = threadIdx.x; c < D2_; c += 256) {
        float acc = 0.f;
        for (int n = 0; n < N_; ++n) acc += y2[(size_t)(b * 24 + s * N_ + n) * D2_ + c];
        real[(size_t)(b * 2 + s) * D2_ + c] = acc * (1.f / 12.f);
    }
}

// ---------------- regressor: build feats + 2-layer MLP ----------------
__global__ void regressor_k(const float* __restrict__ real, const int* __restrict__ input_idx,
                            const float* __restrict__ kwt, const float* __restrict__ other,
                            const float* __restrict__ w1, const float* __restrict__ b1,
                            const float* __restrict__ w2, const float* __restrict__ b2,
                            float* __restrict__ out) {
    int b = blockIdx.x;                  // 8
    int tid = threadIdx.x;               // 256
    __shared__ float feats[RIN_];
    __shared__ float hh[32];
    for (int i = tid; i < RIN_; i += 256) {
        float v;
        if (i < 64) {
            float acc = 0.f;
            for (int m = 0; m < M_; ++m) acc += kwt[input_idx[b * M_ + m] * EK_ + i];
            v = acc * 0.125f;
        } else if (i < 336) {
            v = real[(size_t)(b * 2 + 0) * D2_ + (i - 64)];
        } else if (i < 400) {
            int e = i - 336;
            float acc = 0.f;
            for (int m = 0; m < M_; ++m) acc += kwt[input_idx[64 + b * M_ + m] * EK_ + e];
            v = acc * 0.125f;
        } else if (i < 672) {
            v = real[(size_t)(b * 2 + 1) * D2_ + (i - 400)];
        } else {
            v = other[b * 64 + (i - 672)];
        }
        feats[i] = v;
    }
    __syncthreads();
    if (tid < 32) {
        float acc = b1[tid];
        const float* wr = w1 + (size_t)tid * RIN_;
        for (int i = 0; i < RIN_; ++i) acc += feats[i] * wr[i];
        hh[tid] = fmaxf(acc, 0.f);
    }
    __syncthreads();
    if (tid == 0) {
        float acc = b2[0];
        for (int j = 0; j < 32; ++j) acc += hh[j] * w2[j];
        out[b] = acc;
    }
}

// ---------------- host ----------------
extern "C" void kernel_launch(void* const* d_in, const int* in_sizes, int n_in,
                              void* d_out, int out_size, void* d_ws, size_t ws_size,
                              hipStream_t stream) {
    const int*   chars      = (const int*)d_in[0];
    const int*   att_type   = (const int*)d_in[1];
    const int*   kw_idx     = (const int*)d_in[2];
    const int*   input_idx  = (const int*)d_in[3];
    const float* stat       = (const float*)d_in[4];
    const float* other      = (const float*)d_in[5];
    const float* char_table = (const float*)d_in[6];
    const float* filter_w   = (const float*)d_in[7];
    const float* filter_b   = (const float*)d_in[8];
    const float* gate_w     = (const float*)d_in[9];
    const float* gate_b     = (const float*)d_in[10];
    const float* mlp_w      = (const float*)d_in[11];
    const float* mlp_b      = (const float*)d_in[12];
    const float* kw_table   = (const float*)d_in[13];
    const float* aline_w    = (const float*)d_in[14];
    const float* aline_b    = (const float*)d_in[15];
    const float* t1_attn_w  = (const float*)d_in[16];
    const float* t1_attn_b  = (const float*)d_in[17];
    const float* t1_ffn_w1  = (const float*)d_in[18];
    const float* t1_ffn_b1  = (const float*)d_in[19];
    const float* t1_ffn_w2  = (const float*)d_in[20];
    const float* t1_ffn_b2  = (const float*)d_in[21];
    const float* t1_ln_g    = (const float*)d_in[22];
    const float* t1_ln_b    = (const float*)d_in[23];
    const float* t2_attn_w  = (const float*)d_in[24];
    const float* t2_attn_b  = (const float*)d_in[25];
    const float* t2_ffn_w1  = (const float*)d_in[26];
    const float* t2_ffn_b1  = (const float*)d_in[27];
    const float* t2_ffn_w2  = (const float*)d_in[28];
    const float* t2_ffn_b2  = (const float*)d_in[29];
    const float* t2_ln_g    = (const float*)d_in[30];
    const float* t2_ln_b    = (const float*)d_in[31];
    const float* reg_w1     = (const float*)d_in[32];
    const float* reg_b1     = (const float*)d_in[33];
    const float* reg_w2     = (const float*)d_in[34];
    const float* reg_b2     = (const float*)d_in[35];

    float* ws   = (float*)d_ws;
    float* tblS = ws;                          // 32768
    float* x1   = tblS + 32768;                // 196608
    float* qkv  = x1 + 196608;                 // 589824 (f32)
    float* pbuf = qkv + 589824;                // 786432 (split-K partials)
    float* x2   = pbuf + 786432;               // 52224
    float* realb= x2 + 52224;                  // 4352
    unsigned short* x1b = (unsigned short*)(realb + 4352);   // 196608 shorts
    unsigned short* obb = x1b + 196608;        // 196608 shorts
    unsigned short* hb  = obb + 196608;        // 1572864 shorts
    unsigned short* x2b = hb + 1572864;        // 52224 shorts
    unsigned short* wbf = x2b + 52224 + 16;    // 5441536 shorts (16B aligned pad)
    unsigned short* wb_t1_attn = wbf;
    unsigned short* wb_t1_ffn1 = wbf + 524288;
    unsigned short* wb_t1_ffn2 = wbf + 1572864;
    unsigned short* wb_t2_attn = wbf + 2621440;
    unsigned short* wb_t2_ffn1 = wbf + 3213312;
    unsigned short* wb_t2_ffn2 = wbf + 4327424;
    int* ctr = (int*)(wbf + 5441536);          // work-queue counter (4 B)

    auto gemm_f32 = [&](const unsigned short* A, const unsigned short* Wb, const float* bias,
                        float* Cc, int R, int Kk, int N) {
        dim3 g((N + 63) / 64, R / 64, 1);
        gemm_mfma_k<<<g, 256, 0, stream>>>(A, Wb, bias, Cc, (unsigned short*)0,
                                           R, Kk, N, 0, Kk, 0);
    };
    auto gemm_bf16 = [&](const unsigned short* A, const unsigned short* Wb, const float* bias,
                         unsigned short* Cc, int R, int Kk, int N) {
        dim3 g((N + 63) / 64, R / 64, 1);
        gemm_mfma_k<<<g, 256, 0, stream>>>(A, Wb, bias, (float*)0, Cc,
                                           R, Kk, N, 1, Kk, 1);
    };
    auto gemm_split_ln = [&](const unsigned short* A, const unsigned short* Wb,
                             const float* bias, float* x, unsigned short* xb,
                             const float* g, const float* b,
                             int R, int Kk, int N, int ns) {
        int ksl = ((Kk + ns - 1) / ns + 31) / 32 * 32;
        dim3 gr((N + 63) / 64, R / 64, ns);
        gemm_mfma_k<<<gr, 256, 0, stream>>>(A, Wb, bias, pbuf, (unsigned short*)0,
                                            R, Kk, N, 0, ksl, 0);
        redln_k<<<R, 256, 0, stream>>>(pbuf, bias, x, xb, g, b, N, ns, R * N);
    };

    hipMemsetAsync(ctr, 0, sizeof(int), stream);
    cvt_w_k<<<2048, 256, 0, stream>>>(t1_attn_w, t1_ffn_w1, t1_ffn_w2,
                                      t2_attn_w, t2_ffn_w1, t2_ffn_w2, wbf);
    scale_table_k<<<128, 256, 0, stream>>>(char_table, tblS);
    attvec_k<<<512, 1024, 0, stream>>>(chars, att_type, kw_idx, tblS,
                                       filter_w, filter_b, gate_w, gate_b,
                                       mlp_w, mlp_b, kw_table, aline_w, aline_b,
                                       x1, x1b, ctr);

    // ---- transformer 1: seq=12, batch=64, d=256 ----
    for (int i = 0; i < 2; ++i) {
        const unsigned short* awb = wb_t1_attn + (size_t)i * 4 * C_ * C_;
        const float* ab = t1_attn_b + (size_t)i * 4 * C_;
        gemm_f32(x1b, awb, ab, qkv, 768, C_, 3 * C_);
        attn_k<<<64, 256, 0, stream>>>(qkv, obb, 12, 64, C_, 0.0625f);
        gemm_split_ln(obb, awb + 3 * C_ * C_, ab + 3 * C_, x1, x1b,
                      t1_ln_g + i * 2 * C_, t1_ln_b + i * 2 * C_, 768, C_, C_, 2);
        gemm_bf16(x1b, wb_t1_ffn1 + (size_t)i * FF_ * C_, t1_ffn_b1 + i * FF_, hb, 768, C_, FF_);
        gemm_split_ln(hb, wb_t1_ffn2 + (size_t)i * C_ * FF_, t1_ffn_b2 + i * C_, x1, x1b,
                      t1_ln_g + i * 2 * C_ + C_, t1_ln_b + i * 2 * C_ + C_, 768, FF_, C_, 4);
    }

    build_x2_k<<<192, 256, 0, stream>>>(x1, stat, x2, x2b);

    // ---- transformer 2: seq=8, batch=24, d=272 ----
    float sc2 = 1.0f / sqrtf(272.0f);
    for (int i = 0; i < 2; ++i) {
        const unsigned short* awb = wb_t2_attn + (size_t)i * 4 * D2_ * D2_;
        const float* ab = t2_attn_b + (size_t)i * 4 * D2_;
        gemm_f32(x2b, awb, ab, qkv, 192, D2_, 3 * D2_);
        attn_k<<<24, 256, 0, stream>>>(qkv, obb, 8, 24, D2_, sc2);
        gemm_split_ln(obb, awb + 3 * D2_ * D2_, ab + 3 * D2_, x2, x2b,
                      t2_ln_g + i * 2 * D2_, t2_ln_b + i * 2 * D2_, 192, D2_, D2_, 4);
        gemm_bf16(x2b, wb_t2_ffn1 + (size_t)i * FF_ * D2_, t2_ffn_b1 + i * FF_, hb, 192, D2_, FF_);
        gemm_split_ln(hb, wb_t2_ffn2 + (size_t)i * D2_ * FF_, t2_ffn_b2 + i * D2_, x2, x2b,
                      t2_ln_g + i * 2 * D2_ + D2_, t2_ln_b + i * 2 * D2_ + D2_, 192, FF_, D2_, 8);
    }

    build_real_k<<<16, 256, 0, stream>>>(x2, realb);
    regressor_k<<<8, 256, 0, stream>>>(realb, input_idx, kw_table, other,
                                       reg_w1, reg_b1, reg_w2, reg_b2, (float*)d_out);
}